// Round 13
// baseline (321.319 us; speedup 1.0000x reference)
//
#include <hip/hip_runtime.h>
#include <hip/hip_fp16.h>
#include <cmath>
#include <complex>

#define MULT 64
#define NODE_DIM 576   // 64*(1+3+5)
#define TE 8           // edges per block (tier-B pre kernel)
#define PB 64          // edges per block (pre4 kernel)

typedef _Float16 half8_t __attribute__((ext_vector_type(8)));
typedef _Float16 half4_t __attribute__((ext_vector_type(4)));
typedef float    floatx4 __attribute__((ext_vector_type(4)));

// ---------------------------------------------------------------------------
// Host-side Wigner/CG computation (exact replica of the reference math).
// ---------------------------------------------------------------------------
typedef std::complex<double> cd;

static double factd(int n){ double r=1; for(int i=2;i<=n;i++) r*=(double)i; return r; }

static double su2_cg(int j1,int j2,int j3,int m1,int m2,int m3){
  if(m1+m2!=m3) return 0.0;
  double pref = (2*j3+1)*factd(j1+j2-j3)*factd(j1-j2+j3)*factd(-j1+j2+j3)/factd(j1+j2+j3+1)
              * factd(j1+m1)*factd(j1-m1)*factd(j2+m2)*factd(j2-m2)*factd(j3+m3)*factd(j3-m3);
  pref = std::sqrt(pref);
  double s=0;
  for(int k=0;k<=j1+j2+j3;k++){
    int d0=k, d1=j1+j2-j3-k, d2=j1-m1-k, d3=j2+m2-k, d4=j3-j2+m1+k, d5=j3-j1-m2+k;
    if(d0<0||d1<0||d2<0||d3<0||d4<0||d5<0) continue;
    double denom = factd(d0)*factd(d1)*factd(d2)*factd(d3)*factd(d4)*factd(d5);
    s += ((k&1)?-1.0:1.0)/denom;
  }
  return pref*s;
}

static void make_q(int l, cd q[5][5]){
  for(int i=0;i<5;i++)for(int j=0;j<5;j++) q[i][j]=cd(0,0);
  double s = 1.0/std::sqrt(2.0);
  for(int m=-l;m<0;m++){
    q[l+m][l-m] = cd(s,0);
    q[l+m][l+m] = cd(0,-s);
  }
  q[l][l]=cd(1,0);
  for(int m=1;m<=l;m++){
    double sg = (m&1)?-1.0:1.0;
    q[l+m][l+m]=cd(sg*s,0);
    q[l+m][l-m]=cd(0,sg*s);
  }
  cd ph = (l==0)?cd(1,0) : ((l==1)?cd(0,-1) : cd(-1,0)); // (-i)^l
  for(int i=0;i<2*l+1;i++)for(int j=0;j<2*l+1;j++) q[i][j]*=ph;
}

static void real_cg(int l1,int l2,int l3, double* out){
  int d1=2*l1+1,d2=2*l2+1,d3=2*l3+1;
  double cg[125];
  for(int a=0;a<d1;a++)for(int b=0;b<d2;b++)for(int c=0;c<d3;c++)
    cg[(a*d2+b)*d3+c] = su2_cg(l1,l2,l3,a-l1,b-l2,c-l3);
  cd q1[5][5],q2[5][5],q3[5][5];
  make_q(l1,q1); make_q(l2,q2); make_q(l3,q3);
  cd C[125];
  for(int t=0;t<d1*d2*d3;t++) C[t]=cd(0,0);
  for(int i=0;i<d1;i++)for(int k=0;k<d2;k++)for(int n=0;n<d3;n++){
    double v = cg[(i*d2+k)*d3+n];
    if(v==0.0) continue;
    for(int j=0;j<d1;j++){
      cd a = q1[i][j]*v;
      if(a.real()==0.0 && a.imag()==0.0) continue;
      for(int l=0;l<d2;l++){
        cd b = a*q2[k][l];
        for(int m=0;m<d3;m++) C[(j*d2+l)*d3+m] += b*std::conj(q3[n][m]);
      }
    }
  }
  double sre=0,sim=0;
  for(int t=0;t<d1*d2*d3;t++){ sre+=std::fabs(C[t].real()); sim+=std::fabs(C[t].imag()); }
  bool use_re = (sre>=sim);
  double nrm=0;
  for(int t=0;t<d1*d2*d3;t++){ double x=use_re?C[t].real():C[t].imag(); nrm+=x*x; }
  nrm=std::sqrt(nrm);
  for(int t=0;t<d1*d2*d3;t++){ double x=use_re?C[t].real():C[t].imag(); out[t]=x/nrm; }
}

// Flat CG pack (sizes: 1,9,25,9,9,45,45,25,45,25,125), alpha folded in.
struct CGPack { float v[363]; };

// ---------------------------------------------------------------------------
// Device helpers
// ---------------------------------------------------------------------------
__device__ __forceinline__ float silu_f(float x){ return x/(1.f+expf(-x)); }
__host__ __device__ constexpr int LOFF(int l){ return l==0?0:(l==1?1:4); }

template<int DI,int DJ,int DK>
__device__ __forceinline__ void tp_add(const float* __restrict__ C, const float* xi,
                                       const float* sh, float wn, float* mk){
  float tmp[DK];
#pragma unroll
  for(int c=0;c<DK;c++) tmp[c]=0.f;
#pragma unroll
  for(int a=0;a<DI;a++){
#pragma unroll
    for(int b=0;b<DJ;b++){
      float p = xi[a]*sh[b];
#pragma unroll
      for(int c=0;c<DK;c++) tmp[c] = fmaf(C[(a*DJ+b)*DK+c], p, tmp[c]);
    }
  }
#pragma unroll
  for(int c=0;c<DK;c++) mk[c] = fmaf(wn, tmp[c], mk[c]);
}

// ---------------------------------------------------------------------------
// CSR build kernels
// ---------------------------------------------------------------------------
__global__ void hist_kernel(const int* __restrict__ dst, int* __restrict__ cnt, int E){
  int i = blockIdx.x*blockDim.x + threadIdx.x;
  if(i<E) atomicAdd(&cnt[dst[i]], 1);
}

__global__ __launch_bounds__(1024) void scan_kernel(const int* __restrict__ cnt,
                                                    int* __restrict__ row_ptr, int N){
  __shared__ int s_part[1024];
  const int t = threadIdx.x;
  const int per = (N + 1023) >> 10;
  const int b0 = t*per, b1 = min(N, b0+per);
  int local = 0;
  for(int i=b0;i<b1;i++) local += cnt[i];
  s_part[t] = local;
  __syncthreads();
  for(int off=1; off<1024; off<<=1){
    int v = (t>=off) ? s_part[t-off] : 0;
    __syncthreads();
    s_part[t] += v;
    __syncthreads();
  }
  int run = (t==0) ? 0 : s_part[t-1];
  for(int i=b0;i<b1;i++){ row_ptr[i] = run; run += cnt[i]; }
  if(t==1023) row_ptr[N] = s_part[1023];
}

__global__ void fill_kernel(const int* __restrict__ dst, const int* __restrict__ row_ptr,
                            int* __restrict__ cnt2, int* __restrict__ sorted, int E){
  int i = blockIdx.x*blockDim.x + threadIdx.x;
  if(i<E){
    int d = dst[i];
    int pos = atomicAdd(&cnt2[d], 1);
    sorted[row_ptr[d]+pos] = i;
  }
}

__global__ void sortb_kernel(int* __restrict__ sorted, const int* __restrict__ row_ptr, int N){
  int n = blockIdx.x*blockDim.x + threadIdx.x;
  if(n>=N) return;
  int b=row_ptr[n], e=row_ptr[n+1];
  for(int i=b+1;i<e;i++){
    int v=sorted[i]; int j=i-1;
    while(j>=b && sorted[j]>v){ sorted[j+1]=sorted[j]; j--; }
    sorted[j+1]=v;
  }
}

// rank[e] = CSR position of edge e; src_s[i] = src of i-th sorted edge.
__global__ void rank_kernel(const int* __restrict__ sorted, const int* __restrict__ src_idx,
                            int* __restrict__ rank, int* __restrict__ src_s, int E){
  int i = blockIdx.x*blockDim.x + threadIdx.x;
  if(i<E){ int e = sorted[i]; rank[e] = i; src_s[i] = src_idx[e]; }
}

// Transpose+convert fc_w2 -> w2t[704][64] fp16 (88 KB, one-shot)
__global__ void w2t_kernel(const float* __restrict__ w2, __half* __restrict__ w2t){
  int i = blockIdx.x*256 + threadIdx.x;   // i = col*64 + k
  if(i < 704*64){
    int col = i >> 6, k = i & 63;
    w2t[i] = (__half)w2[k*704 + col];
  }
}

// ---------------------------------------------------------------------------
// pre4: MLP (vector 4x4 reg GEMM) + MFMA for the 64x704 tpw GEMM.
// Outputs written PERMUTED to CSR order via rank[] -> gather reads stream.
// ---------------------------------------------------------------------------
template<typename TW>
__global__ __launch_bounds__(256,2) void emp_pre4_kernel(
  const float* __restrict__ evec, const float* __restrict__ w0,
  const float* __restrict__ w1, const __half* __restrict__ w2t,
  const int* __restrict__ rank,
  TW* __restrict__ tpw, float* __restrict__ shs, int E)
{
  __shared__ float     s_h0T[64][64];   // 16 KB [k][edge]
  __shared__ float     s_tile[64][64];  // 16 KB w1 fp32
  __shared__ _Float16  s_h1h[64][64];   //  8 KB [edge][k] swizzled
  __shared__ _Float16  s_w2t[64][64];   //  8 KB [col][k] swizzled
  __shared__ float     s_d[PB];
  __shared__ int       s_rank[PB];

  const int t   = threadIdx.x;
  const int eg  = t >> 4;
  const int ug  = t & 15;
  const int es0 = eg*4, u0 = ug*4;
  const int e0  = blockIdx.x*PB;

  // --- phase A: dist + SH (to permuted shs) + rank stage; stage w1 -------
  if(t < PB){
    const int e = e0 + t;
    float dist = 0.f;
    int rk = 0;
    if(e < E){
      rk = rank[e];
      float ex=evec[e*3+0], ey=evec[e*3+1], ez=evec[e*3+2];
      dist = sqrtf(ex*ex+ey*ey+ez*ez);
      float inv = 1.f/fmaxf(dist,1e-9f);
      float x=ex*inv, y=ey*inv, z=ez*inv;
      const float s3=1.7320508075688772f, s5=2.2360679774997896f;
      float* srow = shs + (size_t)rk*12;
      srow[0]=1.f;
      srow[1]=s3*y; srow[2]=s3*z; srow[3]=s3*x;
      srow[4]=s5*s3*x*y; srow[5]=s5*s3*y*z; srow[6]=s5*(1.5f*z*z-0.5f);
      srow[7]=s5*s3*x*z; srow[8]=s5*0.5f*s3*(x*x-y*y);
      srow[9]=0.f; srow[10]=0.f; srow[11]=0.f;
    }
    s_d[t] = dist;
    s_rank[t] = rk;
  }
#pragma unroll
  for(int r=0;r<16;r++){ int idx=t+r*256; s_tile[idx>>6][idx&63] = w1[idx]; }
  __syncthreads();

  // --- phase B: h0 transposed --------------------------------------------
#pragma unroll
  for(int r=0;r<16;r++){
    int idx = t + r*256;
    int u = idx>>6, es = idx&63;
    s_h0T[u][es] = silu_f(s_d[es]*w0[u]);
  }
  __syncthreads();

  // --- phase C: h1 = silu((h0 @ w1)/8) -> fp16 LDS, swizzled -------------
  {
    float acc[4][4];
#pragma unroll
    for(int i=0;i<4;i++)
#pragma unroll
      for(int j=0;j<4;j++) acc[i][j]=0.f;
#pragma unroll 4
    for(int k=0;k<64;k++){
      float4 a = *(const float4*)&s_h0T[k][es0];
      float4 b = *(const float4*)&s_tile[k][u0];
      float av[4]={a.x,a.y,a.z,a.w};
      float bv[4]={b.x,b.y,b.z,b.w};
#pragma unroll
      for(int i=0;i<4;i++)
#pragma unroll
        for(int j=0;j<4;j++) acc[i][j]=fmaf(av[i],bv[j],acc[i][j]);
    }
#pragma unroll
    for(int i=0;i<4;i++){
      const int row = es0+i;
      const int ks  = u0 ^ ((row&7)<<3);
      half4_t hv;
#pragma unroll
      for(int j=0;j<4;j++) hv[j] = (_Float16)silu_f(acc[i][j]*0.125f);
      *(half4_t*)&s_h1h[row][ks] = hv;
    }
  }
  __syncthreads();

  // --- A fragments (fixed across all 11 n-blocks) ------------------------
  const int lane = t & 63;
  const int w    = t >> 6;            // wave -> edge-group
  const int lr   = lane & 15;
  const int lk   = lane >> 4;
  half8_t fA0, fA1;
  {
    const int row = w*16 + lr;
    const int swz = (row&7)<<3;
    fA0 = *(half8_t*)&s_h1h[row][(     lk*8) ^ swz];
    fA1 = *(half8_t*)&s_h1h[row][(32 + lk*8) ^ swz];
  }

  // --- phase D: 11 n-blocks via MFMA, permuted writes --------------------
  for(int n=0;n<11;n++){
    __syncthreads();   // previous tile reads done
#pragma unroll
    for(int r=0;r<2;r++){
      int c8  = t + r*256;            // 0..511 chunks of 8 fp16
      int col = c8 >> 3;
      int k8  = (c8 & 7) << 3;
      int ks  = k8 ^ ((col & 7) << 3);
      *(uint4*)&s_w2t[col][ks] =
        *(const uint4*)&w2t[(size_t)(n*64+col)*64 + k8];
    }
    __syncthreads();
#pragma unroll
    for(int cg=0; cg<4; cg++){
      const int colB = cg*16 + lr;
      const int swzB = (colB&7)<<3;
      half8_t fB0 = *(half8_t*)&s_w2t[colB][(     lk*8) ^ swzB];
      half8_t fB1 = *(half8_t*)&s_w2t[colB][(32 + lk*8) ^ swzB];
      floatx4 acc = {0.f,0.f,0.f,0.f};
      acc = __builtin_amdgcn_mfma_f32_16x16x32_f16(fA0, fB0, acc, 0,0,0);
      acc = __builtin_amdgcn_mfma_f32_16x16x32_f16(fA1, fB1, acc, 0,0,0);
#pragma unroll
      for(int r=0;r<4;r++){
        const int el = w*16 + lk*4 + r;
        const int e  = e0 + el;
        if(e < E) tpw[(size_t)s_rank[el]*704 + n*64 + cg*16 + lr] = (TW)(acc[r]*0.125f);
      }
    }
  }
}

// ---------------------------------------------------------------------------
// gather5: wave-per-node H-factorized aggregation, 4-edge software pipeline,
// fully SEQUENTIAL tpw/shs/src streams (CSR-permuted at production).
// ---------------------------------------------------------------------------
template<typename TW>
__global__ __launch_bounds__(256,1) void emp_gather5_kernel(
  const float* __restrict__ nf, const TW* __restrict__ tpw,
  const float* __restrict__ shs, const int* __restrict__ src_s,
  const int* __restrict__ row_ptr, const float* __restrict__ lw,
  float* __restrict__ out, int NN, CGPack cgp)
{
  __shared__ float s_a[4][NODE_DIM];   // per-wave, component-major [r*64+u]
  const int t = threadIdx.x;
  const int u = t & 63;
  const int w = t >> 6;
  const int n = blockIdx.x*4 + w;
  const bool vn = (n < NN);

  float H0[1]={0.f}, H1[3]={0.f}, H2[5]={0.f}, H3[3]={0.f}, H4[9]={0.f},
        H5[9]={0.f}, H6[15]={0.f}, H7[5]={0.f}, H8[15]={0.f},
        H9[25]={0.f}, H10[25]={0.f};

#define ACC(N_, XA, DI, DJ, JO, WN, SH)                                      \
      {                                                                      \
        const float wnl = WN[N_];                                            \
        _Pragma("unroll")                                                    \
        for(int b=0;b<(DJ);b++){                                             \
          float z = wnl*SH[(JO)+b];                                          \
          _Pragma("unroll")                                                  \
          for(int a=0;a<(DI);a++)                                            \
            H##N_[a*(DJ)+b] = fmaf(XA[a], z, H##N_[a*(DJ)+b]);               \
        }                                                                    \
      }
#define ACC_ALL(X0, X1, X2, WN, SH)                                          \
      ACC(0, X0,1,1,0,WN,SH) ACC(1, X0,1,3,1,WN,SH) ACC(2, X0,1,5,4,WN,SH)   \
      ACC(3, X1,3,1,0,WN,SH) ACC(4, X1,3,3,1,WN,SH) ACC(5, X1,3,3,1,WN,SH)   \
      ACC(6, X1,3,5,4,WN,SH) ACC(7, X2,5,1,0,WN,SH) ACC(8, X2,5,3,1,WN,SH)   \
      ACC(9, X2,5,5,4,WN,SH) ACC(10,X2,5,5,4,WN,SH)

#define LOADE(S, I)                                                          \
      const int s##S = __builtin_amdgcn_readfirstlane(src_s[I]);             \
      const float* xr##S = nf + (size_t)s##S*NODE_DIM;                       \
      const TW*    wr##S = tpw + (size_t)(I)*704;                            \
      const float* sr##S = shs + (size_t)(I)*12;                             \
      float x0##S[1]={xr##S[u]};                                             \
      float x1##S[3], x2##S[5], sh##S[9], wn##S[11];                         \
      _Pragma("unroll")                                                      \
      for(int a=0;a<3;a++) x1##S[a]=xr##S[64+u*3+a];                         \
      _Pragma("unroll")                                                      \
      for(int a=0;a<5;a++) x2##S[a]=xr##S[256+u*5+a];                        \
      { float4 p0=*(const float4*)&sr##S[0];                                 \
        float4 p1=*(const float4*)&sr##S[4];                                 \
        float  p2=sr##S[8];                                                  \
        sh##S[0]=p0.x; sh##S[1]=p0.y; sh##S[2]=p0.z; sh##S[3]=p0.w;          \
        sh##S[4]=p1.x; sh##S[5]=p1.y; sh##S[6]=p1.z; sh##S[7]=p1.w;          \
        sh##S[8]=p2; }                                                       \
      _Pragma("unroll")                                                      \
      for(int m=0;m<11;m++) wn##S[m]=(float)wr##S[m*64+u];

  if(vn){
    const int beg = row_ptr[n], end = row_ptr[n+1];
    int i = beg;
    for(; i+3<end; i+=4){
      LOADE(A, i)
      LOADE(B, i+1)
      LOADE(C, i+2)
      LOADE(D, i+3)
      ACC_ALL(x0A,x1A,x2A,wnA,shA)
      ACC_ALL(x0B,x1B,x2B,wnB,shB)
      ACC_ALL(x0C,x1C,x2C,wnC,shC)
      ACC_ALL(x0D,x1D,x2D,wnD,shD)
    }
    for(; i+1<end; i+=2){
      LOADE(A, i)
      LOADE(B, i+1)
      ACC_ALL(x0A,x1A,x2A,wnA,shA)
      ACC_ALL(x0B,x1B,x2B,wnB,shB)
    }
    if(i<end){
      LOADE(A, i)
      ACC_ALL(x0A,x1A,x2A,wnA,shA)
    }
  }
#undef LOADE
#undef ACC_ALL
#undef ACC

  // one CG contraction per node (per thread = per channel u)
  float mg[9];
#pragma unroll
  for(int i=0;i<9;i++) mg[i]=0.f;
#define CGA(N_, DI, DJ, DK, OFF, KO)                                         \
  _Pragma("unroll")                                                          \
  for(int a=0;a<(DI);a++)                                                    \
    _Pragma("unroll")                                                        \
    for(int b=0;b<(DJ);b++){                                                 \
      float h = H##N_[a*(DJ)+b];                                             \
      _Pragma("unroll")                                                      \
      for(int c=0;c<(DK);c++)                                                \
        mg[(KO)+c] = fmaf(cgp.v[(OFF)+(a*(DJ)+b)*(DK)+c], h, mg[(KO)+c]);    \
    }
  CGA(0, 1,1,1, 0,   0)
  CGA(1, 1,3,3, 1,   1)
  CGA(2, 1,5,5, 10,  4)
  CGA(3, 3,1,3, 35,  1)
  CGA(4, 3,3,1, 44,  0)
  CGA(5, 3,3,5, 53,  4)
  CGA(6, 3,5,3, 98,  1)
  CGA(7, 5,1,5, 143, 4)
  CGA(8, 5,3,3, 168, 1)
  CGA(9, 5,5,1, 213, 0)
  CGA(10,5,5,5, 238, 4)
#undef CGA

  s_a[w][u] = mg[0];
#pragma unroll
  for(int d=0;d<3;d++) s_a[w][(1+d)*64+u] = mg[1+d];
#pragma unroll
  for(int d=0;d<5;d++) s_a[w][(4+d)*64+u] = mg[4+d];
  __syncthreads();

  if(vn){
    const int v = u;
    float o0=0.f, o1[3]={0.f,0.f,0.f}, o2[5]={0.f,0.f,0.f,0.f,0.f};
#pragma unroll 8
    for(int uu=0;uu<64;uu++){
      float wv0 = lw[uu*64+v];
      o0 = fmaf(s_a[w][uu], wv0, o0);
      float wv1 = lw[4096+uu*64+v];
#pragma unroll
      for(int d=0;d<3;d++) o1[d]=fmaf(s_a[w][(1+d)*64+uu],wv1,o1[d]);
      float wv2 = lw[8192+uu*64+v];
#pragma unroll
      for(int d=0;d<5;d++) o2[d]=fmaf(s_a[w][(4+d)*64+uu],wv2,o2[d]);
    }
    const float* nrow = nf + (size_t)n*NODE_DIM;
    float* orow = out + (size_t)n*NODE_DIM;
    orow[v] = fmaf(o0,0.125f,nrow[v]);
#pragma unroll
    for(int d=0;d<3;d++) orow[64+v*3+d]=fmaf(o1[d],0.125f,nrow[64+v*3+d]);
#pragma unroll
    for(int d=0;d<5;d++) orow[256+v*5+d]=fmaf(o2[d],0.125f,nrow[256+v*5+d]);
  }
}

// Per-node linear (tier-B only)
__global__ __launch_bounds__(64) void emp_node_kernel(
  const float* __restrict__ nf, const float* __restrict__ lw,
  float* __restrict__ out, int N)
{
  __shared__ float s_a[NODE_DIM];
  const int n = blockIdx.x;
  const int v = threadIdx.x;
  float* orow = out + (size_t)n*NODE_DIM;
#pragma unroll
  for(int r=0;r<9;r++) s_a[r*64+v] = orow[r*64+v];
  __syncthreads();

  float o0=0.f, o1[3]={0.f,0.f,0.f}, o2[5]={0.f,0.f,0.f,0.f,0.f};
#pragma unroll 8
  for(int uu=0;uu<64;uu++){
    float wv0 = lw[uu*64+v];
    o0 = fmaf(s_a[uu], wv0, o0);
    float wv1 = lw[4096+uu*64+v];
#pragma unroll
    for(int d=0;d<3;d++) o1[d]=fmaf(s_a[64+uu*3+d],wv1,o1[d]);
    float wv2 = lw[8192+uu*64+v];
#pragma unroll
    for(int d=0;d<5;d++) o2[d]=fmaf(s_a[256+uu*5+d],wv2,o2[d]);
  }
  const float* nrow = nf + (size_t)n*NODE_DIM;
  orow[v] = fmaf(o0,0.125f,nrow[v]);
#pragma unroll
  for(int d=0;d<3;d++) orow[64+v*3+d]=fmaf(o1[d],0.125f,nrow[64+v*3+d]);
#pragma unroll
  for(int d=0;d<5;d++) orow[256+v*5+d]=fmaf(o2[d],0.125f,nrow[256+v*5+d]);
}

// ---------------------------------------------------------------------------
// TIER B (round-5 verified fallback): pre + gather kernels
// ---------------------------------------------------------------------------
__global__ __launch_bounds__(512,1) void emp_pre_kernel(
  const float* __restrict__ evec, const float* __restrict__ w0,
  const float* __restrict__ w1, float* __restrict__ h1s,
  float* __restrict__ shs, int E)
{
  __shared__ float s_h0[TE][64];
  __shared__ float s_sh[TE][9];
  const int t=threadIdx.x, u=t&63, es=t>>6;
  const int e = blockIdx.x*TE+es;
  const bool valid = (e<E);
  float dist=0.f;
  if(valid){
    float ex=evec[e*3+0], ey=evec[e*3+1], ez=evec[e*3+2];
    dist = sqrtf(ex*ex+ey*ey+ez*ez);
    if(u==0){
      float inv = 1.f/fmaxf(dist,1e-9f);
      float x=ex*inv, y=ey*inv, z=ez*inv;
      const float s3=1.7320508075688772f, s5=2.2360679774997896f;
      s_sh[es][0]=1.f;
      s_sh[es][1]=s3*y; s_sh[es][2]=s3*z; s_sh[es][3]=s3*x;
      s_sh[es][4]=s5*s3*x*y; s_sh[es][5]=s5*s3*y*z; s_sh[es][6]=s5*(1.5f*z*z-0.5f);
      s_sh[es][7]=s5*s3*x*z; s_sh[es][8]=s5*0.5f*s3*(x*x-y*y);
    }
  }
  s_h0[es][u] = silu_f(dist * w0[u]);
  __syncthreads();
  if(valid && u<9) shs[(size_t)e*12+u] = s_sh[es][u];
  float acc = 0.f;
#pragma unroll
  for(int k=0;k<64;k++) acc = fmaf(s_h0[es][k], w1[k*64+u], acc);
  if(valid) h1s[(size_t)e*64+u] = silu_f(acc*0.125f);
}

__global__ __launch_bounds__(256,2) void emp_gather_kernel(
  const float* __restrict__ nf, const float* __restrict__ h1s,
  const float* __restrict__ shs, const int* __restrict__ sorted,
  const int* __restrict__ row_ptr, const int* __restrict__ src_idx,
  const float* __restrict__ w2, float* __restrict__ aggr, CGPack cgp)
{
  __shared__ float s_tile[64][64];
  __shared__ float s_x[8][576];
  __shared__ float s_h1[8][64];
  __shared__ float s_sh[8][12];
  __shared__ int   s_eid[8];
  __shared__ int   s_src[8];
  __shared__ float s_red[4][576];

  const int n = blockIdx.x;
  const int t = threadIdx.x;
  const int u = t & 63;
  const int w = t >> 6;
  const int beg = row_ptr[n], end = row_ptr[n+1];

  float mg[9];
#pragma unroll
  for(int i=0;i<9;i++) mg[i]=0.f;

  for(int base=beg; base<end; base+=8){
    const int C = min(8, end-base);
    if(t < C){ int e = sorted[base+t]; s_eid[t]=e; s_src[t]=src_idx[e]; }
    __syncthreads();
    for(int idx=t; idx<C*576; idx+=256){
      int c = idx/576, j = idx - 576*c;
      s_x[c][j] = nf[(size_t)s_src[c]*NODE_DIM + j];
    }
    for(int idx=t; idx<C*64; idx+=256){
      int c = idx>>6, j = idx&63;
      s_h1[c][j] = h1s[(size_t)s_eid[c]*64 + j];
    }
    if(t < C*12){
      int c = t/12, j = t - 12*c;
      if(j<9) s_sh[c][j] = shs[(size_t)s_eid[c]*12 + j];
    }
    __syncthreads();

#define GI(N_, LI, LJ, LK, OFF)                                              \
    {                                                                        \
      for(int idx=t; idx<4096; idx+=256){                                    \
        int k = idx>>6, j = idx&63;                                          \
        s_tile[k][j] = w2[k*704 + (N_)*64 + j];                              \
      }                                                                      \
      __syncthreads();                                                       \
      for(int c=w; c<C; c+=4){                                               \
        float wn = 0.f;                                                      \
        _Pragma("unroll")                                                    \
        for(int k=0;k<64;k++) wn = fmaf(s_h1[c][k], s_tile[k][u], wn);       \
        wn *= 0.125f;                                                        \
        const int xb = (LI)==0 ? u : ((LI)==1 ? 64+u*3 : 256+u*5);           \
        tp_add<2*(LI)+1,2*(LJ)+1,2*(LK)+1>(cgp.v+(OFF), &s_x[c][xb],         \
                                           &s_sh[c][LOFF(LJ)], wn,           \
                                           mg+LOFF(LK));                     \
      }                                                                      \
      __syncthreads();                                                       \
    }
    GI(0,0,0,0,0)
    GI(1,0,1,1,1)
    GI(2,0,2,2,10)
    GI(3,1,0,1,35)
    GI(4,1,1,0,44)
    GI(5,1,1,2,53)
    GI(6,1,2,1,98)
    GI(7,2,0,2,143)
    GI(8,2,1,1,168)
    GI(9,2,2,0,213)
    GI(10,2,2,2,238)
#undef GI
  }

  s_red[w][u] = mg[0];
#pragma unroll
  for(int a=0;a<3;a++) s_red[w][64+u*3+a] = mg[1+a];
#pragma unroll
  for(int a=0;a<5;a++) s_red[w][256+u*5+a] = mg[4+a];
  __syncthreads();
  float* arow = aggr + (size_t)n*NODE_DIM;
  for(int idx=t; idx<NODE_DIM; idx+=256)
    arow[idx] = s_red[0][idx]+s_red[1][idx]+s_red[2][idx]+s_red[3][idx];
}

// ---------------------------------------------------------------------------
extern "C" void kernel_launch(void* const* d_in, const int* in_sizes, int n_in,
                              void* d_out, int out_size, void* d_ws, size_t ws_size,
                              hipStream_t stream)
{
  const float* nf   = (const float*)d_in[0];
  const int*   eidx = (const int*)  d_in[1];
  const float* evec = (const float*)d_in[2];
  const float* w0   = (const float*)d_in[3];
  const float* w1   = (const float*)d_in[4];
  const float* w2   = (const float*)d_in[5];
  const float* lw   = (const float*)d_in[6];
  const int E = in_sizes[1]/2;
  const int N = in_sizes[0]/NODE_DIM;
  const int* src = eidx;
  const int* dst = eidx + E;

  // Build CG pack (alpha folded in).
  CGPack cgp;
  {
    const int II[11]={0,0,0,1,1,1,1,2,2,2,2};
    const int JJ[11]={0,1,2,0,1,1,2,0,1,2,2};
    const int KK[11]={0,1,2,1,0,2,1,2,1,0,2};
    const int OFF[11]={0,1,10,35,44,53,98,143,168,213,238};
    const double npaths[3]={3.0,4.0,4.0};
    double tmp[125];
    for(int n=0;n<11;n++){
      int li=II[n], lj=JJ[n], lk=KK[n];
      real_cg(li,lj,lk,tmp);
      double alpha = std::sqrt((2.0*lk+1.0)/npaths[lk]);
      int sz=(2*li+1)*(2*lj+1)*(2*lk+1);
      for(int q=0;q<sz;q++) cgp.v[OFF[n]+q]=(float)(tmp[q]*alpha);
    }
  }

  auto align256 = [](size_t x){ return (x + 255) & ~(size_t)255; };

  auto layoutA = [&](size_t elemBytes, size_t& o_tpw, size_t& o_sh, size_t& o_w2t,
                     size_t& o_srt, size_t& o_rnk, size_t& o_srs,
                     size_t& o_cnt, size_t& o_rp)->size_t{
    size_t off = 0;
    o_tpw = off; off = align256(off + (size_t)E*704*elemBytes);
    o_sh  = off; off = align256(off + (size_t)E*12*sizeof(float));
    o_w2t = off; off = align256(off + (size_t)704*64*sizeof(__half));
    o_srt = off; off = align256(off + (size_t)E*sizeof(int));
    o_rnk = off; off = align256(off + (size_t)E*sizeof(int));
    o_srs = off; off = align256(off + (size_t)E*sizeof(int));
    o_cnt = off; off = align256(off + (size_t)N*2*sizeof(int));
    o_rp  = off; off = align256(off + (size_t)(N+1)*sizeof(int));
    return off;
  };
  size_t a32_tpw,a32_sh,a32_w2t,a32_srt,a32_rnk,a32_srs,a32_cnt,a32_rp;
  size_t a16_tpw,a16_sh,a16_w2t,a16_srt,a16_rnk,a16_srs,a16_cnt,a16_rp;
  const size_t needA32 = layoutA(4, a32_tpw,a32_sh,a32_w2t,a32_srt,a32_rnk,a32_srs,a32_cnt,a32_rp);
  const size_t needA16 = layoutA(2, a16_tpw,a16_sh,a16_w2t,a16_srt,a16_rnk,a16_srs,a16_cnt,a16_rp);

  // Tier-B layout: h1s | shs | sorted | cnt+cnt2 | row_ptr
  size_t offB = 0;
  size_t b_h1  = offB; offB = align256(offB + (size_t)E*64*sizeof(float));
  size_t b_sh  = offB; offB = align256(offB + (size_t)E*12*sizeof(float));
  size_t b_srt = offB; offB = align256(offB + (size_t)E*sizeof(int));
  size_t b_cnt = offB; offB = align256(offB + (size_t)N*2*sizeof(int));
  size_t b_rp  = offB; offB = align256(offB + (size_t)(N+1)*sizeof(int));

  char* ws = (char*)d_ws;

  auto runCSR = [&](int* cnt, int* cnt2, int* row_ptr, int* sorted){
    hipMemsetAsync(cnt, 0, (size_t)N*2*sizeof(int), stream);
    hipLaunchKernelGGL(hist_kernel, dim3((E+255)/256), dim3(256), 0, stream,
                       dst, cnt, E);
    hipLaunchKernelGGL(scan_kernel, dim3(1), dim3(1024), 0, stream,
                       cnt, row_ptr, N);
    hipLaunchKernelGGL(fill_kernel, dim3((E+255)/256), dim3(256), 0, stream,
                       dst, row_ptr, cnt2, sorted, E);
    hipLaunchKernelGGL(sortb_kernel, dim3((N+255)/256), dim3(256), 0, stream,
                       sorted, row_ptr, N);
  };

  const int nb3 = (N+3)/4;

  if(ws_size >= needA32){
    float*  tpw    = (float*) (ws + a32_tpw);
    float*  shs    = (float*) (ws + a32_sh);
    __half* w2t    = (__half*)(ws + a32_w2t);
    int*    sorted = (int*)   (ws + a32_srt);
    int*    rank   = (int*)   (ws + a32_rnk);
    int*    src_s  = (int*)   (ws + a32_srs);
    int*    cnt    = (int*)   (ws + a32_cnt);
    int*    cnt2   = cnt + N;
    int*    row_ptr= (int*)   (ws + a32_rp);
    hipLaunchKernelGGL(w2t_kernel, dim3((704*64+255)/256), dim3(256), 0, stream, w2, w2t);
    runCSR(cnt, cnt2, row_ptr, sorted);
    hipLaunchKernelGGL(rank_kernel, dim3((E+255)/256), dim3(256), 0, stream,
                       sorted, src, rank, src_s, E);
    hipLaunchKernelGGL((emp_pre4_kernel<float>), dim3((E+PB-1)/PB), dim3(256), 0, stream,
                       evec, w0, w1, w2t, rank, tpw, shs, E);
    hipLaunchKernelGGL((emp_gather5_kernel<float>), dim3(nb3), dim3(256), 0, stream,
                       nf, tpw, shs, src_s, row_ptr, lw, (float*)d_out, N, cgp);
  } else if(ws_size >= needA16){
    __half* tpw    = (__half*)(ws + a16_tpw);
    float*  shs    = (float*) (ws + a16_sh);
    __half* w2t    = (__half*)(ws + a16_w2t);
    int*    sorted = (int*)   (ws + a16_srt);
    int*    rank   = (int*)   (ws + a16_rnk);
    int*    src_s  = (int*)   (ws + a16_srs);
    int*    cnt    = (int*)   (ws + a16_cnt);
    int*    cnt2   = cnt + N;
    int*    row_ptr= (int*)   (ws + a16_rp);
    hipLaunchKernelGGL(w2t_kernel, dim3((704*64+255)/256), dim3(256), 0, stream, w2, w2t);
    runCSR(cnt, cnt2, row_ptr, sorted);
    hipLaunchKernelGGL(rank_kernel, dim3((E+255)/256), dim3(256), 0, stream,
                       sorted, src, rank, src_s, E);
    hipLaunchKernelGGL((emp_pre4_kernel<__half>), dim3((E+PB-1)/PB), dim3(256), 0, stream,
                       evec, w0, w1, w2t, rank, tpw, shs, E);
    hipLaunchKernelGGL((emp_gather5_kernel<__half>), dim3(nb3), dim3(256), 0, stream,
                       nf, tpw, shs, src_s, row_ptr, lw, (float*)d_out, N, cgp);
  } else {
    // ---------------- TIER B: round-5 verified gather path --------------
    float* h1s    = (float*)(ws + b_h1);
    float* shs    = (float*)(ws + b_sh);
    int*   sorted = (int*)  (ws + b_srt);
    int*   cnt    = (int*)  (ws + b_cnt);
    int*   cnt2   = cnt + N;
    int*   row_ptr= (int*)  (ws + b_rp);
    runCSR(cnt, cnt2, row_ptr, sorted);
    hipLaunchKernelGGL(emp_pre_kernel, dim3((E+TE-1)/TE), dim3(512), 0, stream,
                       evec, w0, w1, h1s, shs, E);
    hipLaunchKernelGGL(emp_gather_kernel, dim3(N), dim3(256), 0, stream,
                       nf, h1s, shs, sorted, row_ptr, src, w2, (float*)d_out, cgp);
    hipLaunchKernelGGL(emp_node_kernel, dim3(N), dim3(64), 0, stream,
                       nf, lw, (float*)d_out, N);
  }
}

// Round 14
// 224.846 us; speedup vs baseline: 1.4291x; 1.4291x over previous
//
#include <hip/hip_runtime.h>
#include <hip/hip_fp16.h>
#include <cmath>
#include <complex>

#define MULT 64
#define NODE_DIM 576   // 64*(1+3+5)
#define TE 8           // edges per block (tier-B pre kernel)
#define PB 64          // edges per block (pre4 kernel)

typedef _Float16 half8_t __attribute__((ext_vector_type(8)));
typedef _Float16 half4_t __attribute__((ext_vector_type(4)));
typedef float    floatx4 __attribute__((ext_vector_type(4)));

// ---------------------------------------------------------------------------
// Host-side Wigner/CG computation (exact replica of the reference math).
// ---------------------------------------------------------------------------
typedef std::complex<double> cd;

static double factd(int n){ double r=1; for(int i=2;i<=n;i++) r*=(double)i; return r; }

static double su2_cg(int j1,int j2,int j3,int m1,int m2,int m3){
  if(m1+m2!=m3) return 0.0;
  double pref = (2*j3+1)*factd(j1+j2-j3)*factd(j1-j2+j3)*factd(-j1+j2+j3)/factd(j1+j2+j3+1)
              * factd(j1+m1)*factd(j1-m1)*factd(j2+m2)*factd(j2-m2)*factd(j3+m3)*factd(j3-m3);
  pref = std::sqrt(pref);
  double s=0;
  for(int k=0;k<=j1+j2+j3;k++){
    int d0=k, d1=j1+j2-j3-k, d2=j1-m1-k, d3=j2+m2-k, d4=j3-j2+m1+k, d5=j3-j1-m2+k;
    if(d0<0||d1<0||d2<0||d3<0||d4<0||d5<0) continue;
    double denom = factd(d0)*factd(d1)*factd(d2)*factd(d3)*factd(d4)*factd(d5);
    s += ((k&1)?-1.0:1.0)/denom;
  }
  return pref*s;
}

static void make_q(int l, cd q[5][5]){
  for(int i=0;i<5;i++)for(int j=0;j<5;j++) q[i][j]=cd(0,0);
  double s = 1.0/std::sqrt(2.0);
  for(int m=-l;m<0;m++){
    q[l+m][l-m] = cd(s,0);
    q[l+m][l+m] = cd(0,-s);
  }
  q[l][l]=cd(1,0);
  for(int m=1;m<=l;m++){
    double sg = (m&1)?-1.0:1.0;
    q[l+m][l+m]=cd(sg*s,0);
    q[l+m][l-m]=cd(0,sg*s);
  }
  cd ph = (l==0)?cd(1,0) : ((l==1)?cd(0,-1) : cd(-1,0)); // (-i)^l
  for(int i=0;i<2*l+1;i++)for(int j=0;j<2*l+1;j++) q[i][j]*=ph;
}

static void real_cg(int l1,int l2,int l3, double* out){
  int d1=2*l1+1,d2=2*l2+1,d3=2*l3+1;
  double cg[125];
  for(int a=0;a<d1;a++)for(int b=0;b<d2;b++)for(int c=0;c<d3;c++)
    cg[(a*d2+b)*d3+c] = su2_cg(l1,l2,l3,a-l1,b-l2,c-l3);
  cd q1[5][5],q2[5][5],q3[5][5];
  make_q(l1,q1); make_q(l2,q2); make_q(l3,q3);
  cd C[125];
  for(int t=0;t<d1*d2*d3;t++) C[t]=cd(0,0);
  for(int i=0;i<d1;i++)for(int k=0;k<d2;k++)for(int n=0;n<d3;n++){
    double v = cg[(i*d2+k)*d3+n];
    if(v==0.0) continue;
    for(int j=0;j<d1;j++){
      cd a = q1[i][j]*v;
      if(a.real()==0.0 && a.imag()==0.0) continue;
      for(int l=0;l<d2;l++){
        cd b = a*q2[k][l];
        for(int m=0;m<d3;m++) C[(j*d2+l)*d3+m] += b*std::conj(q3[n][m]);
      }
    }
  }
  double sre=0,sim=0;
  for(int t=0;t<d1*d2*d3;t++){ sre+=std::fabs(C[t].real()); sim+=std::fabs(C[t].imag()); }
  bool use_re = (sre>=sim);
  double nrm=0;
  for(int t=0;t<d1*d2*d3;t++){ double x=use_re?C[t].real():C[t].imag(); nrm+=x*x; }
  nrm=std::sqrt(nrm);
  for(int t=0;t<d1*d2*d3;t++){ double x=use_re?C[t].real():C[t].imag(); out[t]=x/nrm; }
}

// Flat CG pack (sizes: 1,9,25,9,9,45,45,25,45,25,125), alpha folded in.
struct CGPack { float v[363]; };

// ---------------------------------------------------------------------------
// Device helpers
// ---------------------------------------------------------------------------
__device__ __forceinline__ float silu_f(float x){ return x/(1.f+expf(-x)); }
__host__ __device__ constexpr int LOFF(int l){ return l==0?0:(l==1?1:4); }

template<int DI,int DJ,int DK>
__device__ __forceinline__ void tp_add(const float* __restrict__ C, const float* xi,
                                       const float* sh, float wn, float* mk){
  float tmp[DK];
#pragma unroll
  for(int c=0;c<DK;c++) tmp[c]=0.f;
#pragma unroll
  for(int a=0;a<DI;a++){
#pragma unroll
    for(int b=0;b<DJ;b++){
      float p = xi[a]*sh[b];
#pragma unroll
      for(int c=0;c<DK;c++) tmp[c] = fmaf(C[(a*DJ+b)*DK+c], p, tmp[c]);
    }
  }
#pragma unroll
  for(int c=0;c<DK;c++) mk[c] = fmaf(wn, tmp[c], mk[c]);
}

// ---------------------------------------------------------------------------
// CSR build kernels
// ---------------------------------------------------------------------------
__global__ void hist_kernel(const int* __restrict__ dst, int* __restrict__ cnt, int E){
  int i = blockIdx.x*blockDim.x + threadIdx.x;
  if(i<E) atomicAdd(&cnt[dst[i]], 1);
}

__global__ __launch_bounds__(1024) void scan_kernel(const int* __restrict__ cnt,
                                                    int* __restrict__ row_ptr, int N){
  __shared__ int s_part[1024];
  const int t = threadIdx.x;
  const int per = (N + 1023) >> 10;
  const int b0 = t*per, b1 = min(N, b0+per);
  int local = 0;
  for(int i=b0;i<b1;i++) local += cnt[i];
  s_part[t] = local;
  __syncthreads();
  for(int off=1; off<1024; off<<=1){
    int v = (t>=off) ? s_part[t-off] : 0;
    __syncthreads();
    s_part[t] += v;
    __syncthreads();
  }
  int run = (t==0) ? 0 : s_part[t-1];
  for(int i=b0;i<b1;i++){ row_ptr[i] = run; run += cnt[i]; }
  if(t==1023) row_ptr[N] = s_part[1023];
}

__global__ void fill_kernel(const int* __restrict__ dst, const int* __restrict__ row_ptr,
                            int* __restrict__ cnt2, int* __restrict__ sorted, int E){
  int i = blockIdx.x*blockDim.x + threadIdx.x;
  if(i<E){
    int d = dst[i];
    int pos = atomicAdd(&cnt2[d], 1);
    sorted[row_ptr[d]+pos] = i;
  }
}

__global__ void sortb_kernel(int* __restrict__ sorted, const int* __restrict__ row_ptr, int N){
  int n = blockIdx.x*blockDim.x + threadIdx.x;
  if(n>=N) return;
  int b=row_ptr[n], e=row_ptr[n+1];
  for(int i=b+1;i<e;i++){
    int v=sorted[i]; int j=i-1;
    while(j>=b && sorted[j]>v){ sorted[j+1]=sorted[j]; j--; }
    sorted[j+1]=v;
  }
}

// rank[e] = CSR position of edge e; src_s[i] = src of i-th sorted edge.
__global__ void rank_kernel(const int* __restrict__ sorted, const int* __restrict__ src_idx,
                            int* __restrict__ rank, int* __restrict__ src_s, int E){
  int i = blockIdx.x*blockDim.x + threadIdx.x;
  if(i<E){ int e = sorted[i]; rank[e] = i; src_s[i] = src_idx[e]; }
}

// Transpose+convert fc_w2 -> w2t[704][64] fp16 (88 KB, one-shot)
__global__ void w2t_kernel(const float* __restrict__ w2, __half* __restrict__ w2t){
  int i = blockIdx.x*256 + threadIdx.x;   // i = col*64 + k
  if(i < 704*64){
    int col = i >> 6, k = i & 63;
    w2t[i] = (__half)w2[k*704 + col];
  }
}

// ---------------------------------------------------------------------------
// pre4: MLP (vector 4x4 reg GEMM) + MFMA for the 64x704 tpw GEMM.
// Outputs written PERMUTED to CSR order via rank[] -> gather reads stream.
// ---------------------------------------------------------------------------
template<typename TW>
__global__ __launch_bounds__(256,2) void emp_pre4_kernel(
  const float* __restrict__ evec, const float* __restrict__ w0,
  const float* __restrict__ w1, const __half* __restrict__ w2t,
  const int* __restrict__ rank,
  TW* __restrict__ tpw, float* __restrict__ shs, int E)
{
  __shared__ float     s_h0T[64][64];   // 16 KB [k][edge]
  __shared__ float     s_tile[64][64];  // 16 KB w1 fp32
  __shared__ _Float16  s_h1h[64][64];   //  8 KB [edge][k] swizzled
  __shared__ _Float16  s_w2t[64][64];   //  8 KB [col][k] swizzled
  __shared__ float     s_d[PB];
  __shared__ int       s_rank[PB];

  const int t   = threadIdx.x;
  const int eg  = t >> 4;
  const int ug  = t & 15;
  const int es0 = eg*4, u0 = ug*4;
  const int e0  = blockIdx.x*PB;

  // --- phase A: dist + SH (to permuted shs) + rank stage; stage w1 -------
  if(t < PB){
    const int e = e0 + t;
    float dist = 0.f;
    int rk = 0;
    if(e < E){
      rk = rank[e];
      float ex=evec[e*3+0], ey=evec[e*3+1], ez=evec[e*3+2];
      dist = sqrtf(ex*ex+ey*ey+ez*ez);
      float inv = 1.f/fmaxf(dist,1e-9f);
      float x=ex*inv, y=ey*inv, z=ez*inv;
      const float s3=1.7320508075688772f, s5=2.2360679774997896f;
      float* srow = shs + (size_t)rk*12;
      srow[0]=1.f;
      srow[1]=s3*y; srow[2]=s3*z; srow[3]=s3*x;
      srow[4]=s5*s3*x*y; srow[5]=s5*s3*y*z; srow[6]=s5*(1.5f*z*z-0.5f);
      srow[7]=s5*s3*x*z; srow[8]=s5*0.5f*s3*(x*x-y*y);
      srow[9]=0.f; srow[10]=0.f; srow[11]=0.f;
    }
    s_d[t] = dist;
    s_rank[t] = rk;
  }
#pragma unroll
  for(int r=0;r<16;r++){ int idx=t+r*256; s_tile[idx>>6][idx&63] = w1[idx]; }
  __syncthreads();

  // --- phase B: h0 transposed --------------------------------------------
#pragma unroll
  for(int r=0;r<16;r++){
    int idx = t + r*256;
    int u = idx>>6, es = idx&63;
    s_h0T[u][es] = silu_f(s_d[es]*w0[u]);
  }
  __syncthreads();

  // --- phase C: h1 = silu((h0 @ w1)/8) -> fp16 LDS, swizzled -------------
  {
    float acc[4][4];
#pragma unroll
    for(int i=0;i<4;i++)
#pragma unroll
      for(int j=0;j<4;j++) acc[i][j]=0.f;
#pragma unroll 4
    for(int k=0;k<64;k++){
      float4 a = *(const float4*)&s_h0T[k][es0];
      float4 b = *(const float4*)&s_tile[k][u0];
      float av[4]={a.x,a.y,a.z,a.w};
      float bv[4]={b.x,b.y,b.z,b.w};
#pragma unroll
      for(int i=0;i<4;i++)
#pragma unroll
        for(int j=0;j<4;j++) acc[i][j]=fmaf(av[i],bv[j],acc[i][j]);
    }
#pragma unroll
    for(int i=0;i<4;i++){
      const int row = es0+i;
      const int ks  = u0 ^ ((row&7)<<3);
      half4_t hv;
#pragma unroll
      for(int j=0;j<4;j++) hv[j] = (_Float16)silu_f(acc[i][j]*0.125f);
      *(half4_t*)&s_h1h[row][ks] = hv;
    }
  }
  __syncthreads();

  // --- A fragments (fixed across all 11 n-blocks) ------------------------
  const int lane = t & 63;
  const int w    = t >> 6;            // wave -> edge-group
  const int lr   = lane & 15;
  const int lk   = lane >> 4;
  half8_t fA0, fA1;
  {
    const int row = w*16 + lr;
    const int swz = (row&7)<<3;
    fA0 = *(half8_t*)&s_h1h[row][(     lk*8) ^ swz];
    fA1 = *(half8_t*)&s_h1h[row][(32 + lk*8) ^ swz];
  }

  // --- phase D: 11 n-blocks via MFMA, permuted writes --------------------
  for(int n=0;n<11;n++){
    __syncthreads();   // previous tile reads done
#pragma unroll
    for(int r=0;r<2;r++){
      int c8  = t + r*256;            // 0..511 chunks of 8 fp16
      int col = c8 >> 3;
      int k8  = (c8 & 7) << 3;
      int ks  = k8 ^ ((col & 7) << 3);
      *(uint4*)&s_w2t[col][ks] =
        *(const uint4*)&w2t[(size_t)(n*64+col)*64 + k8];
    }
    __syncthreads();
#pragma unroll
    for(int cg=0; cg<4; cg++){
      const int colB = cg*16 + lr;
      const int swzB = (colB&7)<<3;
      half8_t fB0 = *(half8_t*)&s_w2t[colB][(     lk*8) ^ swzB];
      half8_t fB1 = *(half8_t*)&s_w2t[colB][(32 + lk*8) ^ swzB];
      floatx4 acc = {0.f,0.f,0.f,0.f};
      acc = __builtin_amdgcn_mfma_f32_16x16x32_f16(fA0, fB0, acc, 0,0,0);
      acc = __builtin_amdgcn_mfma_f32_16x16x32_f16(fA1, fB1, acc, 0,0,0);
#pragma unroll
      for(int r=0;r<4;r++){
        const int el = w*16 + lk*4 + r;
        const int e  = e0 + el;
        if(e < E) tpw[(size_t)s_rank[el]*704 + n*64 + cg*16 + lr] = (TW)(acc[r]*0.125f);
      }
    }
  }
}

// ---------------------------------------------------------------------------
// gather6: wave-per-node H-factorized aggregation, 2-edge software pipeline
// (the proven r12 shape), reading SEQUENTIAL CSR-permuted streams.
// ---------------------------------------------------------------------------
template<typename TW>
__global__ __launch_bounds__(256,1) void emp_gather6_kernel(
  const float* __restrict__ nf, const TW* __restrict__ tpw,
  const float* __restrict__ shs, const int* __restrict__ src_s,
  const int* __restrict__ row_ptr, const float* __restrict__ lw,
  float* __restrict__ out, int NN, CGPack cgp)
{
  __shared__ float s_a[4][NODE_DIM];   // per-wave, component-major [r*64+u]
  const int t = threadIdx.x;
  const int u = t & 63;
  const int w = t >> 6;
  const int n = blockIdx.x*4 + w;
  const bool vn = (n < NN);

  float H0[1]={0.f}, H1[3]={0.f}, H2[5]={0.f}, H3[3]={0.f}, H4[9]={0.f},
        H5[9]={0.f}, H6[15]={0.f}, H7[5]={0.f}, H8[15]={0.f},
        H9[25]={0.f}, H10[25]={0.f};

#define ACC(N_, XA, DI, DJ, JO, WN, SH)                                      \
      {                                                                      \
        const float wnl = WN[N_];                                            \
        _Pragma("unroll")                                                    \
        for(int b=0;b<(DJ);b++){                                             \
          float z = wnl*SH[(JO)+b];                                          \
          _Pragma("unroll")                                                  \
          for(int a=0;a<(DI);a++)                                            \
            H##N_[a*(DJ)+b] = fmaf(XA[a], z, H##N_[a*(DJ)+b]);               \
        }                                                                    \
      }
#define ACC_ALL(X0, X1, X2, WN, SH)                                          \
      ACC(0, X0,1,1,0,WN,SH) ACC(1, X0,1,3,1,WN,SH) ACC(2, X0,1,5,4,WN,SH)   \
      ACC(3, X1,3,1,0,WN,SH) ACC(4, X1,3,3,1,WN,SH) ACC(5, X1,3,3,1,WN,SH)   \
      ACC(6, X1,3,5,4,WN,SH) ACC(7, X2,5,1,0,WN,SH) ACC(8, X2,5,3,1,WN,SH)   \
      ACC(9, X2,5,5,4,WN,SH) ACC(10,X2,5,5,4,WN,SH)

#define LOADE(S, I)                                                          \
      const int s##S = __builtin_amdgcn_readfirstlane(src_s[I]);             \
      const float* xr##S = nf + (size_t)s##S*NODE_DIM;                       \
      const TW*    wr##S = tpw + (size_t)(I)*704;                            \
      const float* sr##S = shs + (size_t)(I)*12;                             \
      float x0##S[1]={xr##S[u]};                                             \
      float x1##S[3], x2##S[5], sh##S[9], wn##S[11];                         \
      _Pragma("unroll")                                                      \
      for(int a=0;a<3;a++) x1##S[a]=xr##S[64+u*3+a];                         \
      _Pragma("unroll")                                                      \
      for(int a=0;a<5;a++) x2##S[a]=xr##S[256+u*5+a];                        \
      _Pragma("unroll")                                                      \
      for(int j=0;j<9;j++) sh##S[j]=sr##S[j];                                \
      _Pragma("unroll")                                                      \
      for(int m=0;m<11;m++) wn##S[m]=(float)wr##S[m*64+u];

  if(vn){
    const int beg = row_ptr[n], end = row_ptr[n+1];
    int i = beg;
    for(; i+1<end; i+=2){
      LOADE(A, i)
      LOADE(B, i+1)
      ACC_ALL(x0A,x1A,x2A,wnA,shA)
      ACC_ALL(x0B,x1B,x2B,wnB,shB)
    }
    if(i<end){
      LOADE(A, i)
      ACC_ALL(x0A,x1A,x2A,wnA,shA)
    }
  }
#undef LOADE
#undef ACC_ALL
#undef ACC

  // one CG contraction per node (per thread = per channel u)
  float mg[9];
#pragma unroll
  for(int i=0;i<9;i++) mg[i]=0.f;
#define CGA(N_, DI, DJ, DK, OFF, KO)                                         \
  _Pragma("unroll")                                                          \
  for(int a=0;a<(DI);a++)                                                    \
    _Pragma("unroll")                                                        \
    for(int b=0;b<(DJ);b++){                                                 \
      float h = H##N_[a*(DJ)+b];                                             \
      _Pragma("unroll")                                                      \
      for(int c=0;c<(DK);c++)                                                \
        mg[(KO)+c] = fmaf(cgp.v[(OFF)+(a*(DJ)+b)*(DK)+c], h, mg[(KO)+c]);    \
    }
  CGA(0, 1,1,1, 0,   0)
  CGA(1, 1,3,3, 1,   1)
  CGA(2, 1,5,5, 10,  4)
  CGA(3, 3,1,3, 35,  1)
  CGA(4, 3,3,1, 44,  0)
  CGA(5, 3,3,5, 53,  4)
  CGA(6, 3,5,3, 98,  1)
  CGA(7, 5,1,5, 143, 4)
  CGA(8, 5,3,3, 168, 1)
  CGA(9, 5,5,1, 213, 0)
  CGA(10,5,5,5, 238, 4)
#undef CGA

  s_a[w][u] = mg[0];
#pragma unroll
  for(int d=0;d<3;d++) s_a[w][(1+d)*64+u] = mg[1+d];
#pragma unroll
  for(int d=0;d<5;d++) s_a[w][(4+d)*64+u] = mg[4+d];
  __syncthreads();

  if(vn){
    const int v = u;
    float o0=0.f, o1[3]={0.f,0.f,0.f}, o2[5]={0.f,0.f,0.f,0.f,0.f};
#pragma unroll 8
    for(int uu=0;uu<64;uu++){
      float wv0 = lw[uu*64+v];
      o0 = fmaf(s_a[w][uu], wv0, o0);
      float wv1 = lw[4096+uu*64+v];
#pragma unroll
      for(int d=0;d<3;d++) o1[d]=fmaf(s_a[w][(1+d)*64+uu],wv1,o1[d]);
      float wv2 = lw[8192+uu*64+v];
#pragma unroll
      for(int d=0;d<5;d++) o2[d]=fmaf(s_a[w][(4+d)*64+uu],wv2,o2[d]);
    }
    const float* nrow = nf + (size_t)n*NODE_DIM;
    float* orow = out + (size_t)n*NODE_DIM;
    orow[v] = fmaf(o0,0.125f,nrow[v]);
#pragma unroll
    for(int d=0;d<3;d++) orow[64+v*3+d]=fmaf(o1[d],0.125f,nrow[64+v*3+d]);
#pragma unroll
    for(int d=0;d<5;d++) orow[256+v*5+d]=fmaf(o2[d],0.125f,nrow[256+v*5+d]);
  }
}

// Per-node linear (tier-B only)
__global__ __launch_bounds__(64) void emp_node_kernel(
  const float* __restrict__ nf, const float* __restrict__ lw,
  float* __restrict__ out, int N)
{
  __shared__ float s_a[NODE_DIM];
  const int n = blockIdx.x;
  const int v = threadIdx.x;
  float* orow = out + (size_t)n*NODE_DIM;
#pragma unroll
  for(int r=0;r<9;r++) s_a[r*64+v] = orow[r*64+v];
  __syncthreads();

  float o0=0.f, o1[3]={0.f,0.f,0.f}, o2[5]={0.f,0.f,0.f,0.f,0.f};
#pragma unroll 8
  for(int uu=0;uu<64;uu++){
    float wv0 = lw[uu*64+v];
    o0 = fmaf(s_a[uu], wv0, o0);
    float wv1 = lw[4096+uu*64+v];
#pragma unroll
    for(int d=0;d<3;d++) o1[d]=fmaf(s_a[64+uu*3+d],wv1,o1[d]);
    float wv2 = lw[8192+uu*64+v];
#pragma unroll
    for(int d=0;d<5;d++) o2[d]=fmaf(s_a[256+uu*5+d],wv2,o2[d]);
  }
  const float* nrow = nf + (size_t)n*NODE_DIM;
  orow[v] = fmaf(o0,0.125f,nrow[v]);
#pragma unroll
  for(int d=0;d<3;d++) orow[64+v*3+d]=fmaf(o1[d],0.125f,nrow[64+v*3+d]);
#pragma unroll
  for(int d=0;d<5;d++) orow[256+v*5+d]=fmaf(o2[d],0.125f,nrow[256+v*5+d]);
}

// ---------------------------------------------------------------------------
// TIER B (round-5 verified fallback): pre + gather kernels
// ---------------------------------------------------------------------------
__global__ __launch_bounds__(512,1) void emp_pre_kernel(
  const float* __restrict__ evec, const float* __restrict__ w0,
  const float* __restrict__ w1, float* __restrict__ h1s,
  float* __restrict__ shs, int E)
{
  __shared__ float s_h0[TE][64];
  __shared__ float s_sh[TE][9];
  const int t=threadIdx.x, u=t&63, es=t>>6;
  const int e = blockIdx.x*TE+es;
  const bool valid = (e<E);
  float dist=0.f;
  if(valid){
    float ex=evec[e*3+0], ey=evec[e*3+1], ez=evec[e*3+2];
    dist = sqrtf(ex*ex+ey*ey+ez*ez);
    if(u==0){
      float inv = 1.f/fmaxf(dist,1e-9f);
      float x=ex*inv, y=ey*inv, z=ez*inv;
      const float s3=1.7320508075688772f, s5=2.2360679774997896f;
      s_sh[es][0]=1.f;
      s_sh[es][1]=s3*y; s_sh[es][2]=s3*z; s_sh[es][3]=s3*x;
      s_sh[es][4]=s5*s3*x*y; s_sh[es][5]=s5*s3*y*z; s_sh[es][6]=s5*(1.5f*z*z-0.5f);
      s_sh[es][7]=s5*s3*x*z; s_sh[es][8]=s5*0.5f*s3*(x*x-y*y);
    }
  }
  s_h0[es][u] = silu_f(dist * w0[u]);
  __syncthreads();
  if(valid && u<9) shs[(size_t)e*12+u] = s_sh[es][u];
  float acc = 0.f;
#pragma unroll
  for(int k=0;k<64;k++) acc = fmaf(s_h0[es][k], w1[k*64+u], acc);
  if(valid) h1s[(size_t)e*64+u] = silu_f(acc*0.125f);
}

__global__ __launch_bounds__(256,2) void emp_gather_kernel(
  const float* __restrict__ nf, const float* __restrict__ h1s,
  const float* __restrict__ shs, const int* __restrict__ sorted,
  const int* __restrict__ row_ptr, const int* __restrict__ src_idx,
  const float* __restrict__ w2, float* __restrict__ aggr, CGPack cgp)
{
  __shared__ float s_tile[64][64];
  __shared__ float s_x[8][576];
  __shared__ float s_h1[8][64];
  __shared__ float s_sh[8][12];
  __shared__ int   s_eid[8];
  __shared__ int   s_src[8];
  __shared__ float s_red[4][576];

  const int n = blockIdx.x;
  const int t = threadIdx.x;
  const int u = t & 63;
  const int w = t >> 6;
  const int beg = row_ptr[n], end = row_ptr[n+1];

  float mg[9];
#pragma unroll
  for(int i=0;i<9;i++) mg[i]=0.f;

  for(int base=beg; base<end; base+=8){
    const int C = min(8, end-base);
    if(t < C){ int e = sorted[base+t]; s_eid[t]=e; s_src[t]=src_idx[e]; }
    __syncthreads();
    for(int idx=t; idx<C*576; idx+=256){
      int c = idx/576, j = idx - 576*c;
      s_x[c][j] = nf[(size_t)s_src[c]*NODE_DIM + j];
    }
    for(int idx=t; idx<C*64; idx+=256){
      int c = idx>>6, j = idx&63;
      s_h1[c][j] = h1s[(size_t)s_eid[c]*64 + j];
    }
    if(t < C*12){
      int c = t/12, j = t - 12*c;
      if(j<9) s_sh[c][j] = shs[(size_t)s_eid[c]*12 + j];
    }
    __syncthreads();

#define GI(N_, LI, LJ, LK, OFF)                                              \
    {                                                                        \
      for(int idx=t; idx<4096; idx+=256){                                    \
        int k = idx>>6, j = idx&63;                                          \
        s_tile[k][j] = w2[k*704 + (N_)*64 + j];                              \
      }                                                                      \
      __syncthreads();                                                       \
      for(int c=w; c<C; c+=4){                                               \
        float wn = 0.f;                                                      \
        _Pragma("unroll")                                                    \
        for(int k=0;k<64;k++) wn = fmaf(s_h1[c][k], s_tile[k][u], wn);       \
        wn *= 0.125f;                                                        \
        const int xb = (LI)==0 ? u : ((LI)==1 ? 64+u*3 : 256+u*5);           \
        tp_add<2*(LI)+1,2*(LJ)+1,2*(LK)+1>(cgp.v+(OFF), &s_x[c][xb],         \
                                           &s_sh[c][LOFF(LJ)], wn,           \
                                           mg+LOFF(LK));                     \
      }                                                                      \
      __syncthreads();                                                       \
    }
    GI(0,0,0,0,0)
    GI(1,0,1,1,1)
    GI(2,0,2,2,10)
    GI(3,1,0,1,35)
    GI(4,1,1,0,44)
    GI(5,1,1,2,53)
    GI(6,1,2,1,98)
    GI(7,2,0,2,143)
    GI(8,2,1,1,168)
    GI(9,2,2,0,213)
    GI(10,2,2,2,238)
#undef GI
  }

  s_red[w][u] = mg[0];
#pragma unroll
  for(int a=0;a<3;a++) s_red[w][64+u*3+a] = mg[1+a];
#pragma unroll
  for(int a=0;a<5;a++) s_red[w][256+u*5+a] = mg[4+a];
  __syncthreads();
  float* arow = aggr + (size_t)n*NODE_DIM;
  for(int idx=t; idx<NODE_DIM; idx+=256)
    arow[idx] = s_red[0][idx]+s_red[1][idx]+s_red[2][idx]+s_red[3][idx];
}

// ---------------------------------------------------------------------------
extern "C" void kernel_launch(void* const* d_in, const int* in_sizes, int n_in,
                              void* d_out, int out_size, void* d_ws, size_t ws_size,
                              hipStream_t stream)
{
  const float* nf   = (const float*)d_in[0];
  const int*   eidx = (const int*)  d_in[1];
  const float* evec = (const float*)d_in[2];
  const float* w0   = (const float*)d_in[3];
  const float* w1   = (const float*)d_in[4];
  const float* w2   = (const float*)d_in[5];
  const float* lw   = (const float*)d_in[6];
  const int E = in_sizes[1]/2;
  const int N = in_sizes[0]/NODE_DIM;
  const int* src = eidx;
  const int* dst = eidx + E;

  // Build CG pack (alpha folded in).
  CGPack cgp;
  {
    const int II[11]={0,0,0,1,1,1,1,2,2,2,2};
    const int JJ[11]={0,1,2,0,1,1,2,0,1,2,2};
    const int KK[11]={0,1,2,1,0,2,1,2,1,0,2};
    const int OFF[11]={0,1,10,35,44,53,98,143,168,213,238};
    const double npaths[3]={3.0,4.0,4.0};
    double tmp[125];
    for(int n=0;n<11;n++){
      int li=II[n], lj=JJ[n], lk=KK[n];
      real_cg(li,lj,lk,tmp);
      double alpha = std::sqrt((2.0*lk+1.0)/npaths[lk]);
      int sz=(2*li+1)*(2*lj+1)*(2*lk+1);
      for(int q=0;q<sz;q++) cgp.v[OFF[n]+q]=(float)(tmp[q]*alpha);
    }
  }

  auto align256 = [](size_t x){ return (x + 255) & ~(size_t)255; };

  auto layoutA = [&](size_t elemBytes, size_t& o_tpw, size_t& o_sh, size_t& o_w2t,
                     size_t& o_srt, size_t& o_rnk, size_t& o_srs,
                     size_t& o_cnt, size_t& o_rp)->size_t{
    size_t off = 0;
    o_tpw = off; off = align256(off + (size_t)E*704*elemBytes);
    o_sh  = off; off = align256(off + (size_t)E*12*sizeof(float));
    o_w2t = off; off = align256(off + (size_t)704*64*sizeof(__half));
    o_srt = off; off = align256(off + (size_t)E*sizeof(int));
    o_rnk = off; off = align256(off + (size_t)E*sizeof(int));
    o_srs = off; off = align256(off + (size_t)E*sizeof(int));
    o_cnt = off; off = align256(off + (size_t)N*2*sizeof(int));
    o_rp  = off; off = align256(off + (size_t)(N+1)*sizeof(int));
    return off;
  };
  size_t a32_tpw,a32_sh,a32_w2t,a32_srt,a32_rnk,a32_srs,a32_cnt,a32_rp;
  size_t a16_tpw,a16_sh,a16_w2t,a16_srt,a16_rnk,a16_srs,a16_cnt,a16_rp;
  const size_t needA32 = layoutA(4, a32_tpw,a32_sh,a32_w2t,a32_srt,a32_rnk,a32_srs,a32_cnt,a32_rp);
  const size_t needA16 = layoutA(2, a16_tpw,a16_sh,a16_w2t,a16_srt,a16_rnk,a16_srs,a16_cnt,a16_rp);

  // Tier-B layout: h1s | shs | sorted | cnt+cnt2 | row_ptr
  size_t offB = 0;
  size_t b_h1  = offB; offB = align256(offB + (size_t)E*64*sizeof(float));
  size_t b_sh  = offB; offB = align256(offB + (size_t)E*12*sizeof(float));
  size_t b_srt = offB; offB = align256(offB + (size_t)E*sizeof(int));
  size_t b_cnt = offB; offB = align256(offB + (size_t)N*2*sizeof(int));
  size_t b_rp  = offB; offB = align256(offB + (size_t)(N+1)*sizeof(int));

  char* ws = (char*)d_ws;

  auto runCSR = [&](int* cnt, int* cnt2, int* row_ptr, int* sorted){
    hipMemsetAsync(cnt, 0, (size_t)N*2*sizeof(int), stream);
    hipLaunchKernelGGL(hist_kernel, dim3((E+255)/256), dim3(256), 0, stream,
                       dst, cnt, E);
    hipLaunchKernelGGL(scan_kernel, dim3(1), dim3(1024), 0, stream,
                       cnt, row_ptr, N);
    hipLaunchKernelGGL(fill_kernel, dim3((E+255)/256), dim3(256), 0, stream,
                       dst, row_ptr, cnt2, sorted, E);
    hipLaunchKernelGGL(sortb_kernel, dim3((N+255)/256), dim3(256), 0, stream,
                       sorted, row_ptr, N);
  };

  const int nb3 = (N+3)/4;

  if(ws_size >= needA32){
    float*  tpw    = (float*) (ws + a32_tpw);
    float*  shs    = (float*) (ws + a32_sh);
    __half* w2t    = (__half*)(ws + a32_w2t);
    int*    sorted = (int*)   (ws + a32_srt);
    int*    rank   = (int*)   (ws + a32_rnk);
    int*    src_s  = (int*)   (ws + a32_srs);
    int*    cnt    = (int*)   (ws + a32_cnt);
    int*    cnt2   = cnt + N;
    int*    row_ptr= (int*)   (ws + a32_rp);
    hipLaunchKernelGGL(w2t_kernel, dim3((704*64+255)/256), dim3(256), 0, stream, w2, w2t);
    runCSR(cnt, cnt2, row_ptr, sorted);
    hipLaunchKernelGGL(rank_kernel, dim3((E+255)/256), dim3(256), 0, stream,
                       sorted, src, rank, src_s, E);
    hipLaunchKernelGGL((emp_pre4_kernel<float>), dim3((E+PB-1)/PB), dim3(256), 0, stream,
                       evec, w0, w1, w2t, rank, tpw, shs, E);
    hipLaunchKernelGGL((emp_gather6_kernel<float>), dim3(nb3), dim3(256), 0, stream,
                       nf, tpw, shs, src_s, row_ptr, lw, (float*)d_out, N, cgp);
  } else if(ws_size >= needA16){
    __half* tpw    = (__half*)(ws + a16_tpw);
    float*  shs    = (float*) (ws + a16_sh);
    __half* w2t    = (__half*)(ws + a16_w2t);
    int*    sorted = (int*)   (ws + a16_srt);
    int*    rank   = (int*)   (ws + a16_rnk);
    int*    src_s  = (int*)   (ws + a16_srs);
    int*    cnt    = (int*)   (ws + a16_cnt);
    int*    cnt2   = cnt + N;
    int*    row_ptr= (int*)   (ws + a16_rp);
    hipLaunchKernelGGL(w2t_kernel, dim3((704*64+255)/256), dim3(256), 0, stream, w2, w2t);
    runCSR(cnt, cnt2, row_ptr, sorted);
    hipLaunchKernelGGL(rank_kernel, dim3((E+255)/256), dim3(256), 0, stream,
                       sorted, src, rank, src_s, E);
    hipLaunchKernelGGL((emp_pre4_kernel<__half>), dim3((E+PB-1)/PB), dim3(256), 0, stream,
                       evec, w0, w1, w2t, rank, tpw, shs, E);
    hipLaunchKernelGGL((emp_gather6_kernel<__half>), dim3(nb3), dim3(256), 0, stream,
                       nf, tpw, shs, src_s, row_ptr, lw, (float*)d_out, N, cgp);
  } else {
    // ---------------- TIER B: round-5 verified gather path --------------
    float* h1s    = (float*)(ws + b_h1);
    float* shs    = (float*)(ws + b_sh);
    int*   sorted = (int*)  (ws + b_srt);
    int*   cnt    = (int*)  (ws + b_cnt);
    int*   cnt2   = cnt + N;
    int*   row_ptr= (int*)  (ws + b_rp);
    runCSR(cnt, cnt2, row_ptr, sorted);
    hipLaunchKernelGGL(emp_pre_kernel, dim3((E+TE-1)/TE), dim3(512), 0, stream,
                       evec, w0, w1, h1s, shs, E);
    hipLaunchKernelGGL(emp_gather_kernel, dim3(N), dim3(256), 0, stream,
                       nf, h1s, shs, sorted, row_ptr, src, w2, (float*)d_out, cgp);
    hipLaunchKernelGGL(emp_node_kernel, dim3(N), dim3(64), 0, stream,
                       nf, lw, (float*)d_out, N);
  }
}

// Round 15
// 213.819 us; speedup vs baseline: 1.5028x; 1.0516x over previous
//
#include <hip/hip_runtime.h>
#include <hip/hip_fp16.h>
#include <cmath>
#include <complex>

#define MULT 64
#define NODE_DIM 576   // 64*(1+3+5)
#define TE 8           // edges per block (tier-B pre kernel)
#define PB 64          // edges per block (pre5 kernel)

typedef _Float16 half8_t __attribute__((ext_vector_type(8)));
typedef _Float16 half4_t __attribute__((ext_vector_type(4)));
typedef float    floatx4 __attribute__((ext_vector_type(4)));

// ---------------------------------------------------------------------------
// Host-side Wigner/CG computation (exact replica of the reference math).
// ---------------------------------------------------------------------------
typedef std::complex<double> cd;

static double factd(int n){ double r=1; for(int i=2;i<=n;i++) r*=(double)i; return r; }

static double su2_cg(int j1,int j2,int j3,int m1,int m2,int m3){
  if(m1+m2!=m3) return 0.0;
  double pref = (2*j3+1)*factd(j1+j2-j3)*factd(j1-j2+j3)*factd(-j1+j2+j3)/factd(j1+j2+j3+1)
              * factd(j1+m1)*factd(j1-m1)*factd(j2+m2)*factd(j2-m2)*factd(j3+m3)*factd(j3-m3);
  pref = std::sqrt(pref);
  double s=0;
  for(int k=0;k<=j1+j2+j3;k++){
    int d0=k, d1=j1+j2-j3-k, d2=j1-m1-k, d3=j2+m2-k, d4=j3-j2+m1+k, d5=j3-j1-m2+k;
    if(d0<0||d1<0||d2<0||d3<0||d4<0||d5<0) continue;
    double denom = factd(d0)*factd(d1)*factd(d2)*factd(d3)*factd(d4)*factd(d5);
    s += ((k&1)?-1.0:1.0)/denom;
  }
  return pref*s;
}

static void make_q(int l, cd q[5][5]){
  for(int i=0;i<5;i++)for(int j=0;j<5;j++) q[i][j]=cd(0,0);
  double s = 1.0/std::sqrt(2.0);
  for(int m=-l;m<0;m++){
    q[l+m][l-m] = cd(s,0);
    q[l+m][l+m] = cd(0,-s);
  }
  q[l][l]=cd(1,0);
  for(int m=1;m<=l;m++){
    double sg = (m&1)?-1.0:1.0;
    q[l+m][l+m]=cd(sg*s,0);
    q[l+m][l-m]=cd(0,sg*s);
  }
  cd ph = (l==0)?cd(1,0) : ((l==1)?cd(0,-1) : cd(-1,0)); // (-i)^l
  for(int i=0;i<2*l+1;i++)for(int j=0;j<2*l+1;j++) q[i][j]*=ph;
}

static void real_cg(int l1,int l2,int l3, double* out){
  int d1=2*l1+1,d2=2*l2+1,d3=2*l3+1;
  double cg[125];
  for(int a=0;a<d1;a++)for(int b=0;b<d2;b++)for(int c=0;c<d3;c++)
    cg[(a*d2+b)*d3+c] = su2_cg(l1,l2,l3,a-l1,b-l2,c-l3);
  cd q1[5][5],q2[5][5],q3[5][5];
  make_q(l1,q1); make_q(l2,q2); make_q(l3,q3);
  cd C[125];
  for(int t=0;t<d1*d2*d3;t++) C[t]=cd(0,0);
  for(int i=0;i<d1;i++)for(int k=0;k<d2;k++)for(int n=0;n<d3;n++){
    double v = cg[(i*d2+k)*d3+n];
    if(v==0.0) continue;
    for(int j=0;j<d1;j++){
      cd a = q1[i][j]*v;
      if(a.real()==0.0 && a.imag()==0.0) continue;
      for(int l=0;l<d2;l++){
        cd b = a*q2[k][l];
        for(int m=0;m<d3;m++) C[(j*d2+l)*d3+m] += b*std::conj(q3[n][m]);
      }
    }
  }
  double sre=0,sim=0;
  for(int t=0;t<d1*d2*d3;t++){ sre+=std::fabs(C[t].real()); sim+=std::fabs(C[t].imag()); }
  bool use_re = (sre>=sim);
  double nrm=0;
  for(int t=0;t<d1*d2*d3;t++){ double x=use_re?C[t].real():C[t].imag(); nrm+=x*x; }
  nrm=std::sqrt(nrm);
  for(int t=0;t<d1*d2*d3;t++){ double x=use_re?C[t].real():C[t].imag(); out[t]=x/nrm; }
}

// Flat CG pack (sizes: 1,9,25,9,9,45,45,25,45,25,125), alpha folded in.
struct CGPack { float v[363]; };

// ---------------------------------------------------------------------------
// Device helpers
// ---------------------------------------------------------------------------
__device__ __forceinline__ float silu_f(float x){ return x/(1.f+expf(-x)); }
__host__ __device__ constexpr int LOFF(int l){ return l==0?0:(l==1?1:4); }

template<int DI,int DJ,int DK>
__device__ __forceinline__ void tp_add(const float* __restrict__ C, const float* xi,
                                       const float* sh, float wn, float* mk){
  float tmp[DK];
#pragma unroll
  for(int c=0;c<DK;c++) tmp[c]=0.f;
#pragma unroll
  for(int a=0;a<DI;a++){
#pragma unroll
    for(int b=0;b<DJ;b++){
      float p = xi[a]*sh[b];
#pragma unroll
      for(int c=0;c<DK;c++) tmp[c] = fmaf(C[(a*DJ+b)*DK+c], p, tmp[c]);
    }
  }
#pragma unroll
  for(int c=0;c<DK;c++) mk[c] = fmaf(wn, tmp[c], mk[c]);
}

// ---------------------------------------------------------------------------
// CSR build kernels
// ---------------------------------------------------------------------------
__global__ void hist_kernel(const int* __restrict__ dst, int* __restrict__ cnt, int E){
  int i = blockIdx.x*blockDim.x + threadIdx.x;
  if(i<E) atomicAdd(&cnt[dst[i]], 1);
}

__global__ __launch_bounds__(1024) void scan_kernel(const int* __restrict__ cnt,
                                                    int* __restrict__ row_ptr, int N){
  __shared__ int s_part[1024];
  const int t = threadIdx.x;
  const int per = (N + 1023) >> 10;
  const int b0 = t*per, b1 = min(N, b0+per);
  int local = 0;
  for(int i=b0;i<b1;i++) local += cnt[i];
  s_part[t] = local;
  __syncthreads();
  for(int off=1; off<1024; off<<=1){
    int v = (t>=off) ? s_part[t-off] : 0;
    __syncthreads();
    s_part[t] += v;
    __syncthreads();
  }
  int run = (t==0) ? 0 : s_part[t-1];
  for(int i=b0;i<b1;i++){ row_ptr[i] = run; run += cnt[i]; }
  if(t==1023) row_ptr[N] = s_part[1023];
}

__global__ void fill_kernel(const int* __restrict__ dst, const int* __restrict__ row_ptr,
                            int* __restrict__ cnt2, int* __restrict__ sorted, int E){
  int i = blockIdx.x*blockDim.x + threadIdx.x;
  if(i<E){
    int d = dst[i];
    int pos = atomicAdd(&cnt2[d], 1);
    sorted[row_ptr[d]+pos] = i;
  }
}

__global__ void sortb_kernel(int* __restrict__ sorted, const int* __restrict__ row_ptr, int N){
  int n = blockIdx.x*blockDim.x + threadIdx.x;
  if(n>=N) return;
  int b=row_ptr[n], e=row_ptr[n+1];
  for(int i=b+1;i<e;i++){
    int v=sorted[i]; int j=i-1;
    while(j>=b && sorted[j]>v){ sorted[j+1]=sorted[j]; j--; }
    sorted[j+1]=v;
  }
}

// src_s[i] = src of i-th CSR-sorted edge.
__global__ void srcs_kernel(const int* __restrict__ sorted, const int* __restrict__ src_idx,
                            int* __restrict__ src_s, int E){
  int i = blockIdx.x*blockDim.x + threadIdx.x;
  if(i<E) src_s[i] = src_idx[sorted[i]];
}

// Transpose+convert fc_w2 -> w2t[704][64] fp16 (88 KB, one-shot)
__global__ void w2t_kernel(const float* __restrict__ w2, __half* __restrict__ w2t){
  int i = blockIdx.x*256 + threadIdx.x;   // i = col*64 + k
  if(i < 704*64){
    int col = i >> 6, k = i & 63;
    w2t[i] = (__half)w2[k*704 + col];
  }
}

// ---------------------------------------------------------------------------
// pre5: processes edges IN CSR ORDER (block b handles sorted[b*64..+63]).
// Only evec reads are scattered (12 B/edge); tpw/shs writes are LINEAR, and
// gather6's reads stay LINEAR -> both sides of the 140 MB stream sequential.
// MLP via 4x4 reg GEMM; 64x704 tpw GEMM via MFMA (r12-proven body).
// ---------------------------------------------------------------------------
template<typename TW>
__global__ __launch_bounds__(256,2) void emp_pre5_kernel(
  const float* __restrict__ evec, const float* __restrict__ w0,
  const float* __restrict__ w1, const __half* __restrict__ w2t,
  const int* __restrict__ sorted,
  TW* __restrict__ tpw, float* __restrict__ shs, int E)
{
  __shared__ float     s_h0T[64][64];   // 16 KB [k][edge]
  __shared__ float     s_tile[64][64];  // 16 KB w1 fp32
  __shared__ _Float16  s_h1h[64][64];   //  8 KB [edge][k] swizzled
  __shared__ _Float16  s_w2t[64][64];   //  8 KB [col][k] swizzled
  __shared__ float     s_d[PB];

  const int t   = threadIdx.x;
  const int eg  = t >> 4;
  const int ug  = t & 15;
  const int es0 = eg*4, u0 = ug*4;
  const int e0  = blockIdx.x*PB;        // CSR position base

  // --- phase A: fetch edge id via sorted[], dist + SH -> LINEAR shs ------
  if(t < PB){
    const int i = e0 + t;               // CSR position
    float dist = 0.f;
    if(i < E){
      const int eid = sorted[i];
      float ex=evec[eid*3+0], ey=evec[eid*3+1], ez=evec[eid*3+2];
      dist = sqrtf(ex*ex+ey*ey+ez*ez);
      float inv = 1.f/fmaxf(dist,1e-9f);
      float x=ex*inv, y=ey*inv, z=ez*inv;
      const float s3=1.7320508075688772f, s5=2.2360679774997896f;
      float* srow = shs + (size_t)i*12;
      srow[0]=1.f;
      srow[1]=s3*y; srow[2]=s3*z; srow[3]=s3*x;
      srow[4]=s5*s3*x*y; srow[5]=s5*s3*y*z; srow[6]=s5*(1.5f*z*z-0.5f);
      srow[7]=s5*s3*x*z; srow[8]=s5*0.5f*s3*(x*x-y*y);
      srow[9]=0.f; srow[10]=0.f; srow[11]=0.f;
    }
    s_d[t] = dist;
  }
#pragma unroll
  for(int r=0;r<16;r++){ int idx=t+r*256; s_tile[idx>>6][idx&63] = w1[idx]; }
  __syncthreads();

  // --- phase B: h0 transposed --------------------------------------------
#pragma unroll
  for(int r=0;r<16;r++){
    int idx = t + r*256;
    int u = idx>>6, es = idx&63;
    s_h0T[u][es] = silu_f(s_d[es]*w0[u]);
  }
  __syncthreads();

  // --- phase C: h1 = silu((h0 @ w1)/8) -> fp16 LDS, swizzled -------------
  {
    float acc[4][4];
#pragma unroll
    for(int i=0;i<4;i++)
#pragma unroll
      for(int j=0;j<4;j++) acc[i][j]=0.f;
#pragma unroll 4
    for(int k=0;k<64;k++){
      float4 a = *(const float4*)&s_h0T[k][es0];
      float4 b = *(const float4*)&s_tile[k][u0];
      float av[4]={a.x,a.y,a.z,a.w};
      float bv[4]={b.x,b.y,b.z,b.w};
#pragma unroll
      for(int i=0;i<4;i++)
#pragma unroll
        for(int j=0;j<4;j++) acc[i][j]=fmaf(av[i],bv[j],acc[i][j]);
    }
#pragma unroll
    for(int i=0;i<4;i++){
      const int row = es0+i;
      const int ks  = u0 ^ ((row&7)<<3);
      half4_t hv;
#pragma unroll
      for(int j=0;j<4;j++) hv[j] = (_Float16)silu_f(acc[i][j]*0.125f);
      *(half4_t*)&s_h1h[row][ks] = hv;
    }
  }
  __syncthreads();

  // --- A fragments (fixed across all 11 n-blocks) ------------------------
  const int lane = t & 63;
  const int w    = t >> 6;            // wave -> edge-group
  const int lr   = lane & 15;
  const int lk   = lane >> 4;
  half8_t fA0, fA1;
  {
    const int row = w*16 + lr;
    const int swz = (row&7)<<3;
    fA0 = *(half8_t*)&s_h1h[row][(     lk*8) ^ swz];
    fA1 = *(half8_t*)&s_h1h[row][(32 + lk*8) ^ swz];
  }

  // --- phase D: 11 n-blocks via MFMA, LINEAR writes ----------------------
  for(int n=0;n<11;n++){
    __syncthreads();   // previous tile reads done
#pragma unroll
    for(int r=0;r<2;r++){
      int c8  = t + r*256;            // 0..511 chunks of 8 fp16
      int col = c8 >> 3;
      int k8  = (c8 & 7) << 3;
      int ks  = k8 ^ ((col & 7) << 3);
      *(uint4*)&s_w2t[col][ks] =
        *(const uint4*)&w2t[(size_t)(n*64+col)*64 + k8];
    }
    __syncthreads();
#pragma unroll
    for(int cg=0; cg<4; cg++){
      const int colB = cg*16 + lr;
      const int swzB = (colB&7)<<3;
      half8_t fB0 = *(half8_t*)&s_w2t[colB][(     lk*8) ^ swzB];
      half8_t fB1 = *(half8_t*)&s_w2t[colB][(32 + lk*8) ^ swzB];
      floatx4 acc = {0.f,0.f,0.f,0.f};
      acc = __builtin_amdgcn_mfma_f32_16x16x32_f16(fA0, fB0, acc, 0,0,0);
      acc = __builtin_amdgcn_mfma_f32_16x16x32_f16(fA1, fB1, acc, 0,0,0);
#pragma unroll
      for(int r=0;r<4;r++){
        const int i = e0 + w*16 + lk*4 + r;   // CSR position (linear)
        if(i < E) tpw[(size_t)i*704 + n*64 + cg*16 + lr] = (TW)(acc[r]*0.125f);
      }
    }
  }
}

// ---------------------------------------------------------------------------
// gather6: wave-per-node H-factorized aggregation, 2-edge software pipeline
// (the proven r12 shape), reading SEQUENTIAL CSR-permuted streams.
// ---------------------------------------------------------------------------
template<typename TW>
__global__ __launch_bounds__(256,1) void emp_gather6_kernel(
  const float* __restrict__ nf, const TW* __restrict__ tpw,
  const float* __restrict__ shs, const int* __restrict__ src_s,
  const int* __restrict__ row_ptr, const float* __restrict__ lw,
  float* __restrict__ out, int NN, CGPack cgp)
{
  __shared__ float s_a[4][NODE_DIM];   // per-wave, component-major [r*64+u]
  const int t = threadIdx.x;
  const int u = t & 63;
  const int w = t >> 6;
  const int n = blockIdx.x*4 + w;
  const bool vn = (n < NN);

  float H0[1]={0.f}, H1[3]={0.f}, H2[5]={0.f}, H3[3]={0.f}, H4[9]={0.f},
        H5[9]={0.f}, H6[15]={0.f}, H7[5]={0.f}, H8[15]={0.f},
        H9[25]={0.f}, H10[25]={0.f};

#define ACC(N_, XA, DI, DJ, JO, WN, SH)                                      \
      {                                                                      \
        const float wnl = WN[N_];                                            \
        _Pragma("unroll")                                                    \
        for(int b=0;b<(DJ);b++){                                             \
          float z = wnl*SH[(JO)+b];                                          \
          _Pragma("unroll")                                                  \
          for(int a=0;a<(DI);a++)                                            \
            H##N_[a*(DJ)+b] = fmaf(XA[a], z, H##N_[a*(DJ)+b]);               \
        }                                                                    \
      }
#define ACC_ALL(X0, X1, X2, WN, SH)                                          \
      ACC(0, X0,1,1,0,WN,SH) ACC(1, X0,1,3,1,WN,SH) ACC(2, X0,1,5,4,WN,SH)   \
      ACC(3, X1,3,1,0,WN,SH) ACC(4, X1,3,3,1,WN,SH) ACC(5, X1,3,3,1,WN,SH)   \
      ACC(6, X1,3,5,4,WN,SH) ACC(7, X2,5,1,0,WN,SH) ACC(8, X2,5,3,1,WN,SH)   \
      ACC(9, X2,5,5,4,WN,SH) ACC(10,X2,5,5,4,WN,SH)

#define LOADE(S, I)                                                          \
      const int s##S = __builtin_amdgcn_readfirstlane(src_s[I]);             \
      const float* xr##S = nf + (size_t)s##S*NODE_DIM;                       \
      const TW*    wr##S = tpw + (size_t)(I)*704;                            \
      const float* sr##S = shs + (size_t)(I)*12;                             \
      float x0##S[1]={xr##S[u]};                                             \
      float x1##S[3], x2##S[5], sh##S[9], wn##S[11];                         \
      _Pragma("unroll")                                                      \
      for(int a=0;a<3;a++) x1##S[a]=xr##S[64+u*3+a];                         \
      _Pragma("unroll")                                                      \
      for(int a=0;a<5;a++) x2##S[a]=xr##S[256+u*5+a];                        \
      _Pragma("unroll")                                                      \
      for(int j=0;j<9;j++) sh##S[j]=sr##S[j];                                \
      _Pragma("unroll")                                                      \
      for(int m=0;m<11;m++) wn##S[m]=(float)wr##S[m*64+u];

  if(vn){
    const int beg = row_ptr[n], end = row_ptr[n+1];
    int i = beg;
    for(; i+1<end; i+=2){
      LOADE(A, i)
      LOADE(B, i+1)
      ACC_ALL(x0A,x1A,x2A,wnA,shA)
      ACC_ALL(x0B,x1B,x2B,wnB,shB)
    }
    if(i<end){
      LOADE(A, i)
      ACC_ALL(x0A,x1A,x2A,wnA,shA)
    }
  }
#undef LOADE
#undef ACC_ALL
#undef ACC

  // one CG contraction per node (per thread = per channel u)
  float mg[9];
#pragma unroll
  for(int i=0;i<9;i++) mg[i]=0.f;
#define CGA(N_, DI, DJ, DK, OFF, KO)                                         \
  _Pragma("unroll")                                                          \
  for(int a=0;a<(DI);a++)                                                    \
    _Pragma("unroll")                                                        \
    for(int b=0;b<(DJ);b++){                                                 \
      float h = H##N_[a*(DJ)+b];                                             \
      _Pragma("unroll")                                                      \
      for(int c=0;c<(DK);c++)                                                \
        mg[(KO)+c] = fmaf(cgp.v[(OFF)+(a*(DJ)+b)*(DK)+c], h, mg[(KO)+c]);    \
    }
  CGA(0, 1,1,1, 0,   0)
  CGA(1, 1,3,3, 1,   1)
  CGA(2, 1,5,5, 10,  4)
  CGA(3, 3,1,3, 35,  1)
  CGA(4, 3,3,1, 44,  0)
  CGA(5, 3,3,5, 53,  4)
  CGA(6, 3,5,3, 98,  1)
  CGA(7, 5,1,5, 143, 4)
  CGA(8, 5,3,3, 168, 1)
  CGA(9, 5,5,1, 213, 0)
  CGA(10,5,5,5, 238, 4)
#undef CGA

  s_a[w][u] = mg[0];
#pragma unroll
  for(int d=0;d<3;d++) s_a[w][(1+d)*64+u] = mg[1+d];
#pragma unroll
  for(int d=0;d<5;d++) s_a[w][(4+d)*64+u] = mg[4+d];
  __syncthreads();

  if(vn){
    const int v = u;
    float o0=0.f, o1[3]={0.f,0.f,0.f}, o2[5]={0.f,0.f,0.f,0.f,0.f};
#pragma unroll 8
    for(int uu=0;uu<64;uu++){
      float wv0 = lw[uu*64+v];
      o0 = fmaf(s_a[w][uu], wv0, o0);
      float wv1 = lw[4096+uu*64+v];
#pragma unroll
      for(int d=0;d<3;d++) o1[d]=fmaf(s_a[w][(1+d)*64+uu],wv1,o1[d]);
      float wv2 = lw[8192+uu*64+v];
#pragma unroll
      for(int d=0;d<5;d++) o2[d]=fmaf(s_a[w][(4+d)*64+uu],wv2,o2[d]);
    }
    const float* nrow = nf + (size_t)n*NODE_DIM;
    float* orow = out + (size_t)n*NODE_DIM;
    orow[v] = fmaf(o0,0.125f,nrow[v]);
#pragma unroll
    for(int d=0;d<3;d++) orow[64+v*3+d]=fmaf(o1[d],0.125f,nrow[64+v*3+d]);
#pragma unroll
    for(int d=0;d<5;d++) orow[256+v*5+d]=fmaf(o2[d],0.125f,nrow[256+v*5+d]);
  }
}

// Per-node linear (tier-B only)
__global__ __launch_bounds__(64) void emp_node_kernel(
  const float* __restrict__ nf, const float* __restrict__ lw,
  float* __restrict__ out, int N)
{
  __shared__ float s_a[NODE_DIM];
  const int n = blockIdx.x;
  const int v = threadIdx.x;
  float* orow = out + (size_t)n*NODE_DIM;
#pragma unroll
  for(int r=0;r<9;r++) s_a[r*64+v] = orow[r*64+v];
  __syncthreads();

  float o0=0.f, o1[3]={0.f,0.f,0.f}, o2[5]={0.f,0.f,0.f,0.f,0.f};
#pragma unroll 8
  for(int uu=0;uu<64;uu++){
    float wv0 = lw[uu*64+v];
    o0 = fmaf(s_a[uu], wv0, o0);
    float wv1 = lw[4096+uu*64+v];
#pragma unroll
    for(int d=0;d<3;d++) o1[d]=fmaf(s_a[64+uu*3+d],wv1,o1[d]);
    float wv2 = lw[8192+uu*64+v];
#pragma unroll
    for(int d=0;d<5;d++) o2[d]=fmaf(s_a[256+uu*5+d],wv2,o2[d]);
  }
  const float* nrow = nf + (size_t)n*NODE_DIM;
  orow[v] = fmaf(o0,0.125f,nrow[v]);
#pragma unroll
  for(int d=0;d<3;d++) orow[64+v*3+d]=fmaf(o1[d],0.125f,nrow[64+v*3+d]);
#pragma unroll
  for(int d=0;d<5;d++) orow[256+v*5+d]=fmaf(o2[d],0.125f,nrow[256+v*5+d]);
}

// ---------------------------------------------------------------------------
// TIER B (round-5 verified fallback): pre + gather kernels
// ---------------------------------------------------------------------------
__global__ __launch_bounds__(512,1) void emp_pre_kernel(
  const float* __restrict__ evec, const float* __restrict__ w0,
  const float* __restrict__ w1, float* __restrict__ h1s,
  float* __restrict__ shs, int E)
{
  __shared__ float s_h0[TE][64];
  __shared__ float s_sh[TE][9];
  const int t=threadIdx.x, u=t&63, es=t>>6;
  const int e = blockIdx.x*TE+es;
  const bool valid = (e<E);
  float dist=0.f;
  if(valid){
    float ex=evec[e*3+0], ey=evec[e*3+1], ez=evec[e*3+2];
    dist = sqrtf(ex*ex+ey*ey+ez*ez);
    if(u==0){
      float inv = 1.f/fmaxf(dist,1e-9f);
      float x=ex*inv, y=ey*inv, z=ez*inv;
      const float s3=1.7320508075688772f, s5=2.2360679774997896f;
      s_sh[es][0]=1.f;
      s_sh[es][1]=s3*y; s_sh[es][2]=s3*z; s_sh[es][3]=s3*x;
      s_sh[es][4]=s5*s3*x*y; s_sh[es][5]=s5*s3*y*z; s_sh[es][6]=s5*(1.5f*z*z-0.5f);
      s_sh[es][7]=s5*s3*x*z; s_sh[es][8]=s5*0.5f*s3*(x*x-y*y);
    }
  }
  s_h0[es][u] = silu_f(dist * w0[u]);
  __syncthreads();
  if(valid && u<9) shs[(size_t)e*12+u] = s_sh[es][u];
  float acc = 0.f;
#pragma unroll
  for(int k=0;k<64;k++) acc = fmaf(s_h0[es][k], w1[k*64+u], acc);
  if(valid) h1s[(size_t)e*64+u] = silu_f(acc*0.125f);
}

__global__ __launch_bounds__(256,2) void emp_gather_kernel(
  const float* __restrict__ nf, const float* __restrict__ h1s,
  const float* __restrict__ shs, const int* __restrict__ sorted,
  const int* __restrict__ row_ptr, const int* __restrict__ src_idx,
  const float* __restrict__ w2, float* __restrict__ aggr, CGPack cgp)
{
  __shared__ float s_tile[64][64];
  __shared__ float s_x[8][576];
  __shared__ float s_h1[8][64];
  __shared__ float s_sh[8][12];
  __shared__ int   s_eid[8];
  __shared__ int   s_src[8];
  __shared__ float s_red[4][576];

  const int n = blockIdx.x;
  const int t = threadIdx.x;
  const int u = t & 63;
  const int w = t >> 6;
  const int beg = row_ptr[n], end = row_ptr[n+1];

  float mg[9];
#pragma unroll
  for(int i=0;i<9;i++) mg[i]=0.f;

  for(int base=beg; base<end; base+=8){
    const int C = min(8, end-base);
    if(t < C){ int e = sorted[base+t]; s_eid[t]=e; s_src[t]=src_idx[e]; }
    __syncthreads();
    for(int idx=t; idx<C*576; idx+=256){
      int c = idx/576, j = idx - 576*c;
      s_x[c][j] = nf[(size_t)s_src[c]*NODE_DIM + j];
    }
    for(int idx=t; idx<C*64; idx+=256){
      int c = idx>>6, j = idx&63;
      s_h1[c][j] = h1s[(size_t)s_eid[c]*64 + j];
    }
    if(t < C*12){
      int c = t/12, j = t - 12*c;
      if(j<9) s_sh[c][j] = shs[(size_t)s_eid[c]*12 + j];
    }
    __syncthreads();

#define GI(N_, LI, LJ, LK, OFF)                                              \
    {                                                                        \
      for(int idx=t; idx<4096; idx+=256){                                    \
        int k = idx>>6, j = idx&63;                                          \
        s_tile[k][j] = w2[k*704 + (N_)*64 + j];                              \
      }                                                                      \
      __syncthreads();                                                       \
      for(int c=w; c<C; c+=4){                                               \
        float wn = 0.f;                                                      \
        _Pragma("unroll")                                                    \
        for(int k=0;k<64;k++) wn = fmaf(s_h1[c][k], s_tile[k][u], wn);       \
        wn *= 0.125f;                                                        \
        const int xb = (LI)==0 ? u : ((LI)==1 ? 64+u*3 : 256+u*5);           \
        tp_add<2*(LI)+1,2*(LJ)+1,2*(LK)+1>(cgp.v+(OFF), &s_x[c][xb],         \
                                           &s_sh[c][LOFF(LJ)], wn,           \
                                           mg+LOFF(LK));                     \
      }                                                                      \
      __syncthreads();                                                       \
    }
    GI(0,0,0,0,0)
    GI(1,0,1,1,1)
    GI(2,0,2,2,10)
    GI(3,1,0,1,35)
    GI(4,1,1,0,44)
    GI(5,1,1,2,53)
    GI(6,1,2,1,98)
    GI(7,2,0,2,143)
    GI(8,2,1,1,168)
    GI(9,2,2,0,213)
    GI(10,2,2,2,238)
#undef GI
  }

  s_red[w][u] = mg[0];
#pragma unroll
  for(int a=0;a<3;a++) s_red[w][64+u*3+a] = mg[1+a];
#pragma unroll
  for(int a=0;a<5;a++) s_red[w][256+u*5+a] = mg[4+a];
  __syncthreads();
  float* arow = aggr + (size_t)n*NODE_DIM;
  for(int idx=t; idx<NODE_DIM; idx+=256)
    arow[idx] = s_red[0][idx]+s_red[1][idx]+s_red[2][idx]+s_red[3][idx];
}

// ---------------------------------------------------------------------------
extern "C" void kernel_launch(void* const* d_in, const int* in_sizes, int n_in,
                              void* d_out, int out_size, void* d_ws, size_t ws_size,
                              hipStream_t stream)
{
  const float* nf   = (const float*)d_in[0];
  const int*   eidx = (const int*)  d_in[1];
  const float* evec = (const float*)d_in[2];
  const float* w0   = (const float*)d_in[3];
  const float* w1   = (const float*)d_in[4];
  const float* w2   = (const float*)d_in[5];
  const float* lw   = (const float*)d_in[6];
  const int E = in_sizes[1]/2;
  const int N = in_sizes[0]/NODE_DIM;
  const int* src = eidx;
  const int* dst = eidx + E;

  // Build CG pack (alpha folded in).
  CGPack cgp;
  {
    const int II[11]={0,0,0,1,1,1,1,2,2,2,2};
    const int JJ[11]={0,1,2,0,1,1,2,0,1,2,2};
    const int KK[11]={0,1,2,1,0,2,1,2,1,0,2};
    const int OFF[11]={0,1,10,35,44,53,98,143,168,213,238};
    const double npaths[3]={3.0,4.0,4.0};
    double tmp[125];
    for(int n=0;n<11;n++){
      int li=II[n], lj=JJ[n], lk=KK[n];
      real_cg(li,lj,lk,tmp);
      double alpha = std::sqrt((2.0*lk+1.0)/npaths[lk]);
      int sz=(2*li+1)*(2*lj+1)*(2*lk+1);
      for(int q=0;q<sz;q++) cgp.v[OFF[n]+q]=(float)(tmp[q]*alpha);
    }
  }

  auto align256 = [](size_t x){ return (x + 255) & ~(size_t)255; };

  auto layoutA = [&](size_t elemBytes, size_t& o_tpw, size_t& o_sh, size_t& o_w2t,
                     size_t& o_srt, size_t& o_srs,
                     size_t& o_cnt, size_t& o_rp)->size_t{
    size_t off = 0;
    o_tpw = off; off = align256(off + (size_t)E*704*elemBytes);
    o_sh  = off; off = align256(off + (size_t)E*12*sizeof(float));
    o_w2t = off; off = align256(off + (size_t)704*64*sizeof(__half));
    o_srt = off; off = align256(off + (size_t)E*sizeof(int));
    o_srs = off; off = align256(off + (size_t)E*sizeof(int));
    o_cnt = off; off = align256(off + (size_t)N*2*sizeof(int));
    o_rp  = off; off = align256(off + (size_t)(N+1)*sizeof(int));
    return off;
  };
  size_t a32_tpw,a32_sh,a32_w2t,a32_srt,a32_srs,a32_cnt,a32_rp;
  size_t a16_tpw,a16_sh,a16_w2t,a16_srt,a16_srs,a16_cnt,a16_rp;
  const size_t needA32 = layoutA(4, a32_tpw,a32_sh,a32_w2t,a32_srt,a32_srs,a32_cnt,a32_rp);
  const size_t needA16 = layoutA(2, a16_tpw,a16_sh,a16_w2t,a16_srt,a16_srs,a16_cnt,a16_rp);

  // Tier-B layout: h1s | shs | sorted | cnt+cnt2 | row_ptr
  size_t offB = 0;
  size_t b_h1  = offB; offB = align256(offB + (size_t)E*64*sizeof(float));
  size_t b_sh  = offB; offB = align256(offB + (size_t)E*12*sizeof(float));
  size_t b_srt = offB; offB = align256(offB + (size_t)E*sizeof(int));
  size_t b_cnt = offB; offB = align256(offB + (size_t)N*2*sizeof(int));
  size_t b_rp  = offB; offB = align256(offB + (size_t)(N+1)*sizeof(int));

  char* ws = (char*)d_ws;

  auto runCSR = [&](int* cnt, int* cnt2, int* row_ptr, int* sorted){
    hipMemsetAsync(cnt, 0, (size_t)N*2*sizeof(int), stream);
    hipLaunchKernelGGL(hist_kernel, dim3((E+255)/256), dim3(256), 0, stream,
                       dst, cnt, E);
    hipLaunchKernelGGL(scan_kernel, dim3(1), dim3(1024), 0, stream,
                       cnt, row_ptr, N);
    hipLaunchKernelGGL(fill_kernel, dim3((E+255)/256), dim3(256), 0, stream,
                       dst, row_ptr, cnt2, sorted, E);
    hipLaunchKernelGGL(sortb_kernel, dim3((N+255)/256), dim3(256), 0, stream,
                       sorted, row_ptr, N);
  };

  const int nb3 = (N+3)/4;

  if(ws_size >= needA32){
    float*  tpw    = (float*) (ws + a32_tpw);
    float*  shs    = (float*) (ws + a32_sh);
    __half* w2t    = (__half*)(ws + a32_w2t);
    int*    sorted = (int*)   (ws + a32_srt);
    int*    src_s  = (int*)   (ws + a32_srs);
    int*    cnt    = (int*)   (ws + a32_cnt);
    int*    cnt2   = cnt + N;
    int*    row_ptr= (int*)   (ws + a32_rp);
    hipLaunchKernelGGL(w2t_kernel, dim3((704*64+255)/256), dim3(256), 0, stream, w2, w2t);
    runCSR(cnt, cnt2, row_ptr, sorted);
    hipLaunchKernelGGL(srcs_kernel, dim3((E+255)/256), dim3(256), 0, stream,
                       sorted, src, src_s, E);
    hipLaunchKernelGGL((emp_pre5_kernel<float>), dim3((E+PB-1)/PB), dim3(256), 0, stream,
                       evec, w0, w1, w2t, sorted, tpw, shs, E);
    hipLaunchKernelGGL((emp_gather6_kernel<float>), dim3(nb3), dim3(256), 0, stream,
                       nf, tpw, shs, src_s, row_ptr, lw, (float*)d_out, N, cgp);
  } else if(ws_size >= needA16){
    __half* tpw    = (__half*)(ws + a16_tpw);
    float*  shs    = (float*) (ws + a16_sh);
    __half* w2t    = (__half*)(ws + a16_w2t);
    int*    sorted = (int*)   (ws + a16_srt);
    int*    src_s  = (int*)   (ws + a16_srs);
    int*    cnt    = (int*)   (ws + a16_cnt);
    int*    cnt2   = cnt + N;
    int*    row_ptr= (int*)   (ws + a16_rp);
    hipLaunchKernelGGL(w2t_kernel, dim3((704*64+255)/256), dim3(256), 0, stream, w2, w2t);
    runCSR(cnt, cnt2, row_ptr, sorted);
    hipLaunchKernelGGL(srcs_kernel, dim3((E+255)/256), dim3(256), 0, stream,
                       sorted, src, src_s, E);
    hipLaunchKernelGGL((emp_pre5_kernel<__half>), dim3((E+PB-1)/PB), dim3(256), 0, stream,
                       evec, w0, w1, w2t, sorted, tpw, shs, E);
    hipLaunchKernelGGL((emp_gather6_kernel<__half>), dim3(nb3), dim3(256), 0, stream,
                       nf, tpw, shs, src_s, row_ptr, lw, (float*)d_out, N, cgp);
  } else {
    // ---------------- TIER B: round-5 verified gather path --------------
    float* h1s    = (float*)(ws + b_h1);
    float* shs    = (float*)(ws + b_sh);
    int*   sorted = (int*)  (ws + b_srt);
    int*   cnt    = (int*)  (ws + b_cnt);
    int*   cnt2   = cnt + N;
    int*   row_ptr= (int*)  (ws + b_rp);
    runCSR(cnt, cnt2, row_ptr, sorted);
    hipLaunchKernelGGL(emp_pre_kernel, dim3((E+TE-1)/TE), dim3(512), 0, stream,
                       evec, w0, w1, h1s, shs, E);
    hipLaunchKernelGGL(emp_gather_kernel, dim3(N), dim3(256), 0, stream,
                       nf, h1s, shs, sorted, row_ptr, src, w2, (float*)d_out, cgp);
    hipLaunchKernelGGL(emp_node_kernel, dim3(N), dim3(64), 0, stream,
                       nf, lw, (float*)d_out, N);
  }
}